// Round 8
// baseline (1242.922 us; speedup 1.0000x reference)
//
#include <hip/hip_runtime.h>
#include <hip/hip_bf16.h>
#include <math.h>

// ---------------- problem constants ----------------
#define B_SZ   2
#define NTOK   4097      // n = 4096 + cls
#define KLEN   4105      // n + mem_len(8)
#define KLEN_PAD 4160    // 65 * 64
#define DMODEL 512
#define INDIM  1024
#define NHEAD  8
#define DHEAD  64
#define MLPD   2048
#define MEMLEN 8
#define NEG_BIG  -1.0e30f
#define CSCALE 0.18033688f   // (1/sqrt(64)) * log2(e); softmax runs in log2 domain
#define NQT 65               // q-tiles of 64
#define SPLIT_MID 33         // split0: tiles [0,33), split1: [33,65)

typedef unsigned short ushort_t;
typedef short bf16x8 __attribute__((ext_vector_type(8)));
typedef float f32x4  __attribute__((ext_vector_type(4)));

__device__ __forceinline__ unsigned short f2bf(float f) {
    union { float f; unsigned u; } v; v.f = f;
    const unsigned r = v.u + 0x7fff + ((v.u >> 16) & 1);   // RTNE
    return (unsigned short)(r >> 16);
}
__device__ __forceinline__ unsigned short f2bf_rhu(float f) {   // cheap round (P in [0,1])
    union { float f; unsigned u; } v; v.f = f;
    return (unsigned short)((v.u + 0x8000u) >> 16);
}
__device__ __forceinline__ float bf2f(unsigned short u) {
    union { unsigned u; float f; } v; v.u = ((unsigned)u) << 16;
    return v.f;
}

// async global->LDS, 16B per lane; lds base must be wave-uniform
__device__ __forceinline__ void gload_lds16(const void* g, void* l) {
    __builtin_amdgcn_global_load_lds(
        (const __attribute__((address_space(1))) unsigned int*)g,
        (__attribute__((address_space(3))) unsigned int*)l, 16, 0, 0);
}

// ---------------- small helpers ----------------
__device__ __forceinline__ float block_reduce_sum_256(float v, float* sh) {
    #pragma unroll
    for (int m = 1; m < 64; m <<= 1) v += __shfl_xor(v, m);
    const int w = threadIdx.x >> 6;
    if ((threadIdx.x & 63) == 0) sh[w] = v;
    __syncthreads();
    float r = sh[0] + sh[1] + sh[2] + sh[3];
    __syncthreads();
    return r;
}

// ---------------- pos emb (fast trig) ----------------
__global__ void k_pos(float* __restrict__ pos) {
    const int p = blockIdx.x;
    const int j = threadIdx.x;
    const float position = (float)(KLEN - 1 - p);
    const float inv_freq = exp2f(-(float)j * 0.051905126f);   // 10000^(-j/256)
    const float x = position * inv_freq;
    pos[(long)p * DMODEL + j]       = __sinf(x);
    pos[(long)p * DMODEL + 256 + j] = __cosf(x);
}

// ---------------- cls token ----------------
__global__ void k_cls(const float* __restrict__ cls, float* __restrict__ x) {
    const int b = blockIdx.x;
    x[(long)b * NTOK * DMODEL + threadIdx.x] = cls[threadIdx.x];
}

// ---------------- fp32 -> bf16 convert ----------------
__global__ __launch_bounds__(256)
void k_f2b(const float* __restrict__ in, ushort_t* __restrict__ out, long n4) {
    for (long i = blockIdx.x * 256 + threadIdx.x; i < n4; i += (long)gridDim.x * 256) {
        const float4 f = ((const float4*)in)[i];
        ushort4 u;
        u.x = f2bf(f.x); u.y = f2bf(f.y); u.z = f2bf(f.z); u.w = f2bf(f.w);
        ((ushort4*)out)[i] = u;
    }
}

// ---------------- weight fp32[K][N] -> bf16 Wt[N][K] ----------------
__global__ __launch_bounds__(256)
void k_w2bt(const float* __restrict__ W, ushort_t* __restrict__ Wt, int K, int N) {
    __shared__ float tile[64][65];
    W  += (long)blockIdx.z * K * N;
    Wt += (long)blockIdx.z * N * K;
    const int n0 = blockIdx.x * 64, k0 = blockIdx.y * 64;
    const int t = threadIdx.x;
    #pragma unroll
    for (int rep = 0; rep < 16; ++rep) {
        const int idx = rep * 256 + t;
        const int r = idx >> 6, c = idx & 63;
        tile[r][c] = W[(long)(k0 + r) * N + n0 + c];
    }
    __syncthreads();
    #pragma unroll
    for (int rep = 0; rep < 16; ++rep) {
        const int idx = rep * 256 + t;
        const int n = idx >> 6, kk = idx & 63;
        Wt[(long)(n0 + n) * K + k0 + kk] = f2bf(tile[kk][n]);
    }
}

// ---------------- bf16 MFMA GEMM ----------------
enum { EPI_NONE = 0, EPI_BIAS_RELU = 1, EPI_BIAS_GELU = 2, EPI_BIAS_RES = 3 };

template <int EPI, int OBF16>
__global__ __launch_bounds__(256)
void k_gemm_bf(const ushort_t* __restrict__ A, const ushort_t* __restrict__ Wt,
               const float* __restrict__ bias, void* __restrict__ Cv,
               int M, int K, int N, long ldc, long sAb, long sCb)
{
    __shared__ ushort_t As[128 * 64];
    __shared__ ushort_t Bs[128 * 64];
    const int t    = threadIdx.x;
    const int lane = t & 63;
    const int w    = t >> 6;
    const int l15  = lane & 15;
    const int lhi  = lane >> 4;
    const int wr   = w >> 1, wc = w & 1;
    const long bm = (long)blockIdx.y * 128, bn = (long)blockIdx.x * 128;
    A += (long)blockIdx.z * sAb;
    float*    Cf = (float*)Cv    + (long)blockIdx.z * sCb;
    ushort_t* Cb = (ushort_t*)Cv + (long)blockIdx.z * sCb;

    int srow[4], scol[4];
    #pragma unroll
    for (int i = 0; i < 4; ++i) {
        const int c = i * 256 + t;
        srow[i] = c >> 3;
        scol[i] = ((c & 7) ^ (srow[i] & 7)) << 3;
    }

    f32x4 acc[4][4] = {};

    for (int k0 = 0; k0 < K; k0 += 64) {
        __syncthreads();
        #pragma unroll
        for (int i = 0; i < 4; ++i) {
            long ar = bm + srow[i]; if (ar >= M) ar = M - 1;
            gload_lds16(A + ar * (long)K + k0 + scol[i],
                        &As[(i * 256 + (t & ~63)) * 8]);
        }
        #pragma unroll
        for (int i = 0; i < 4; ++i) {
            gload_lds16(Wt + (bn + srow[i]) * (long)K + k0 + scol[i],
                        &Bs[(i * 256 + (t & ~63)) * 8]);
        }
        asm volatile("s_waitcnt vmcnt(0)" ::: "memory");
        __syncthreads();

        #pragma unroll
        for (int ks = 0; ks < 2; ++ks) {
            bf16x8 af[4], bfr[4];
            #pragma unroll
            for (int m = 0; m < 4; ++m) {
                const int row = wr * 64 + m * 16 + l15;
                const int cb  = (ks * 64 + lhi * 16) ^ ((row & 7) << 4);
                af[m] = *(const bf16x8*)((const char*)As + row * 128 + cb);
            }
            #pragma unroll
            for (int n = 0; n < 4; ++n) {
                const int row = wc * 64 + n * 16 + l15;
                const int cb  = (ks * 64 + lhi * 16) ^ ((row & 7) << 4);
                bfr[n] = *(const bf16x8*)((const char*)Bs + row * 128 + cb);
            }
            #pragma unroll
            for (int m = 0; m < 4; ++m)
                #pragma unroll
                for (int n = 0; n < 4; ++n)
                    acc[m][n] = __builtin_amdgcn_mfma_f32_16x16x32_bf16(af[m], bfr[n], acc[m][n], 0, 0, 0);
        }
    }

    #pragma unroll
    for (int m = 0; m < 4; ++m) {
        #pragma unroll
        for (int j = 0; j < 4; ++j) {
            const long mg = bm + wr * 64 + m * 16 + lhi * 4 + j;
            if (mg < M) {
                #pragma unroll
                for (int n = 0; n < 4; ++n) {
                    const long ng = bn + wc * 64 + n * 16 + l15;
                    float r = acc[m][n][j];
                    if (EPI != EPI_NONE) r += bias[ng];
                    if (EPI == EPI_BIAS_RELU) r = fmaxf(r, 0.f);
                    if (EPI == EPI_BIAS_GELU) r = 0.5f * r * (1.f + erff(r * 0.70710678118654752f));
                    if (OBF16) Cb[mg * ldc + ng] = f2bf(r);
                    else if (EPI == EPI_BIAS_RES) Cf[mg * ldc + ng] += r;
                    else Cf[mg * ldc + ng] = r;
                }
            }
        }
    }
}

// ---------------- GEMV (M=1 per batch) ----------------
template <int EPI, int OBF16>
__global__ __launch_bounds__(256)
void k_gemv(const ushort_t* __restrict__ A, const ushort_t* __restrict__ Wt,
            const float* __restrict__ bias, void* __restrict__ Cv,
            int K, int N, long sA, long sC)
{
    const int b = blockIdx.y;
    const int n = blockIdx.x * 64 + (threadIdx.x >> 2);
    const int j = threadIdx.x & 3;
    const ushort_t* a = A + (long)b * sA;
    const ushort_t* wv = Wt + (long)n * K;
    float sum = 0.f;
    for (int k0 = j * 8; k0 < K; k0 += 32) {
        const bf16x8 av = *(const bf16x8*)(a + k0);
        const bf16x8 wr = *(const bf16x8*)(wv + k0);
        #pragma unroll
        for (int e = 0; e < 8; ++e)
            sum += bf2f((ushort_t)av[e]) * bf2f((ushort_t)wr[e]);
    }
    sum += __shfl_xor(sum, 1);
    sum += __shfl_xor(sum, 2);
    if (j == 0 && n < N) {
        float r = sum;
        if (EPI != EPI_NONE) r += bias[n];
        if (EPI == EPI_BIAS_GELU) r = 0.5f * r * (1.f + erff(r * 0.70710678118654752f));
        if (OBF16) ((ushort_t*)Cv)[(long)b * sC + n] = f2bf(r);
        else if (EPI == EPI_BIAS_RES) ((float*)Cv)[(long)b * sC + n] += r;
        else ((float*)Cv)[(long)b * sC + n] = r;
    }
}

// ---------------- LayerNorm, bf16 out ----------------
__global__ __launch_bounds__(256)
void k_ln(const float* __restrict__ x, ushort_t* __restrict__ y,
          const float* __restrict__ g, const float* __restrict__ b, long rstride)
{
    __shared__ float sh[4];
    const long row = (long)blockIdx.x * rstride;
    const float* xr = x + row * DMODEL;
    const int t = threadIdx.x;
    const float v0 = xr[t], v1 = xr[t + 256];
    const float s  = block_reduce_sum_256(v0 + v1, sh);
    const float s2 = block_reduce_sum_256(v0 * v0 + v1 * v1, sh);
    const float mu = s * (1.f / DMODEL);
    const float var = s2 * (1.f / DMODEL) - mu * mu;
    const float rs = rsqrtf(var + 1e-5f);
    y[row * DMODEL + t]       = f2bf((v0 - mu) * rs * g[t] + b[t]);
    y[row * DMODEL + t + 256] = f2bf((v1 - mu) * rs * g[t + 256] + b[t + 256]);
}

// ---------------- build bf16 K rows (pre-scaled by CSCALE): [b][klen][512] ----------------
__global__ __launch_bounds__(256)
void k_build_k(const ushort_t* __restrict__ qkvb, const float* __restrict__ mems,
               const float* __restrict__ pos, ushort_t* __restrict__ kf, int layer)
{
    const int b = blockIdx.y;
    const long idx = (long)blockIdx.x * 256 + threadIdx.x;   // over KLEN*128
    const int j  = (int)(idx >> 7);
    const int d0 = (int)(idx & 127) * 4;
    if (j >= KLEN) return;
    float v0, v1, v2, v3;
    if (j < NTOK) {
        const ushort_t* s = qkvb + ((long)b * NTOK + j) * 1536 + 512 + d0;
        v0 = bf2f(s[0]); v1 = bf2f(s[1]); v2 = bf2f(s[2]); v3 = bf2f(s[3]);
    } else {
        const float* mb = mems + (((long)layer * B_SZ + b) * MEMLEN + (j - NTOK)) * DMODEL + d0;
        v0 = mb[0]; v1 = mb[1]; v2 = mb[2]; v3 = mb[3];
    }
    const float4 pe = *(const float4*)(pos + (long)j * DMODEL + d0);
    ushort4 o;
    o.x = f2bf((v0 + pe.x) * CSCALE);
    o.y = f2bf((v1 + pe.y) * CSCALE);
    o.z = f2bf((v2 + pe.z) * CSCALE);
    o.w = f2bf((v3 + pe.w) * CSCALE);
    *(ushort4*)(kf + ((long)b * KLEN + j) * DMODEL + d0) = o;
}

// ---------------- build bf16 V transposed: [b*8+h][d=64][KLEN_PAD] ----------------
__global__ __launch_bounds__(256)
void k_build_vt(const ushort_t* __restrict__ qkvb, const float* __restrict__ mems,
                const float* __restrict__ pos, ushort_t* __restrict__ vt, int layer)
{
    __shared__ ushort_t tile[64][65];
    const int jb = blockIdx.x * 64;
    const int b  = blockIdx.y;
    const int h  = blockIdx.z;
    const int t  = threadIdx.x;
    #pragma unroll
    for (int rep = 0; rep < 16; ++rep) {
        const int idx = rep * 256 + t;
        const int r = idx >> 6, c = idx & 63;
        const int j = jb + r;
        float val = 0.f;
        if (j < NTOK)
            val = bf2f(qkvb[((long)b * NTOK + j) * 1536 + 1024 + h * 64 + c]) + pos[(long)j * DMODEL + h * 64 + c];
        else if (j < KLEN)
            val = mems[(((long)layer * B_SZ + b) * MEMLEN + (j - NTOK)) * DMODEL + h * 64 + c]
                + pos[(long)j * DMODEL + h * 64 + c];
        tile[c][r] = f2bf(val);
    }
    __syncthreads();
    #pragma unroll
    for (int rep = 0; rep < 16; ++rep) {
        const int idx = rep * 256 + t;
        const int d = idx >> 6, r = idx & 63;
        vt[(((long)b * NHEAD + h) * 64 + d) * (long)KLEN_PAD + jb + r] = tile[d][r];
    }
}

// ---------------- MFMA flash attention, KV-split=2, partial outputs ----------------
// grid: (NQT, 16, B_SZ); blockIdx.y = split*8 + h. Round-3/4 proven structure.
#define LDSP 72

__global__ __launch_bounds__(256)
void k_attn_sp(const ushort_t* __restrict__ qkvb,
               const ushort_t* __restrict__ kf,
               const ushort_t* __restrict__ vt,
               ushort_t* __restrict__ part0,
               ushort_t* __restrict__ part1,
               float2* __restrict__ ml)
{
    __shared__ ushort_t QPs[64][LDSP];  // Q at start, then reused as P
    __shared__ ushort_t Ks [64][LDSP];
    __shared__ ushort_t Vts[64][LDSP];

    const int t     = threadIdx.x;
    const int lane  = t & 63;
    const int w     = t >> 6;
    const int l15   = lane & 15;
    const int lhi   = lane >> 4;
    const int qt    = blockIdx.x;
    const int qb    = qt * 64;
    const int split = blockIdx.y >> 3;
    const int h     = blockIdx.y & 7;
    const int b     = blockIdx.z;
    const int ktBeg = split ? SPLIT_MID : 0;
    const int ktEnd = split ? NQT : SPLIT_MID;
    ushort_t* part  = split ? part1 : part0;

    // ---- stage Q ----
    {
        const int r  = t >> 2;
        const int c0 = (t & 3) * 16;
        const int qg = qb + r;
        uint4 u0 = make_uint4(0,0,0,0), u1 = make_uint4(0,0,0,0);
        if (qg < NTOK) {
            const ushort_t* src = qkvb + ((long)b * NTOK + qg) * 1536 + h * 64 + c0;
            u0 = ((const uint4*)src)[0];
            u1 = ((const uint4*)src)[1];
        }
        *(uint4*)&QPs[r][c0]     = u0;
        *(uint4*)&QPs[r][c0 + 8] = u1;
    }
    __syncthreads();
    bf16x8 q_frag[2];
    #pragma unroll
    for (int ks = 0; ks < 2; ++ks)
        q_frag[ks] = *(const bf16x8*)&QPs[w * 16 + l15][ks * 32 + lhi * 8];

    f32x4 o_frag[4] = {};
    float m_run[4] = {NEG_BIG, NEG_BIG, NEG_BIG, NEG_BIG};
    float l_run[4] = {0.f, 0.f, 0.f, 0.f};

    const ushort_t* kbase = kf + (long)b * KLEN * DMODEL + h * 64;
    const ushort_t* vbase = vt + ((long)b * NHEAD + h) * 64 * (long)KLEN_PAD;

    for (int kt = ktBeg; kt < ktEnd; ++kt) {
        const int kb = kt * 64;
        __syncthreads();   // prev tile fully consumed
        {
            const int r = t >> 2;
            const int jg = kb + r;
            #pragma unroll
            for (int cc = 0; cc < 2; ++cc) {
                const int c8 = (t & 3) * 2 + cc;
                uint4 kv = make_uint4(0u, 0u, 0u, 0u);
                if (jg < KLEN) kv = *(const uint4*)(kbase + (long)jg * DMODEL + c8 * 8);
                *(uint4*)&Ks[r][c8 * 8] = kv;
                const uint4 vv = *(const uint4*)(vbase + (long)r * KLEN_PAD + kb + c8 * 8);
                *(uint4*)&Vts[r][c8 * 8] = vv;
            }
        }
        __syncthreads();

        // ---- S = Q @ K^T (log2 domain; scale folded into K) ----
        f32x4 s_frag[4];
        #pragma unroll
        for (int n = 0; n < 4; ++n) {
            f32x4 acc = {0.f, 0.f, 0.f, 0.f};
            #pragma unroll
            for (int ks = 0; ks < 2; ++ks) {
                const bf16x8 kfr = *(const bf16x8*)&Ks[n * 16 + l15][ks * 32 + lhi * 8];
                acc = __builtin_amdgcn_mfma_f32_16x16x32_bf16(q_frag[ks], kfr, acc, 0, 0, 0);
            }
            s_frag[n] = acc;
        }

        // ---- online softmax (exp2); mask only in global tail tile ----
        #pragma unroll
        for (int i = 0; i < 4; ++i) {
            float sv[4];
            #pragma unroll
            for (int n = 0; n < 4; ++n) sv[n] = s_frag[n][i];
            if (kt == NQT - 1) {
                #pragma unroll
                for (int n = 0; n < 4; ++n)
                    if (kb + n * 16 + l15 >= KLEN) sv[n] = NEG_BIG;
            }
            float mx = fmaxf(fmaxf(sv[0], sv[1]), fmaxf(sv[2], sv[3]));
            mx = fmaxf(mx, __shfl_xor(mx, 1));
            mx = fmaxf(mx, __shfl_xor(mx, 2));
            mx = fmaxf(mx, __shfl_xor(mx, 4));
            mx = fmaxf(mx, __shfl_xor(mx, 8));
            const float mnew  = fmaxf(m_run[i], mx);
            const float alpha = exp2f(m_run[i] - mnew);
            float lsum = 0.f;
            ushort_t pb[4];
            #pragma unroll
            for (int n = 0; n < 4; ++n) {
                const float p = exp2f(sv[n] - mnew);
                lsum += p;
                pb[n] = f2bf_rhu(p);
            }
            lsum += __shfl_xor(lsum, 1);
            lsum += __shfl_xor(lsum, 2);
            lsum += __shfl_xor(lsum, 4);
            lsum += __shfl_xor(lsum, 8);
            l_run[i] = l_run[i] * alpha + lsum;
            m_run[i] = mnew;
            #pragma unroll
            for (int n = 0; n < 4; ++n) {
                o_frag[n][i] *= alpha;
                QPs[w * 16 + lhi * 4 + i][n * 16 + l15] = pb[n];   // wave-private strip
            }
        }
        __syncthreads();   // P visible

        // ---- O += P @ V ----
        #pragma unroll
        for (int n = 0; n < 4; ++n) {
            #pragma unroll
            for (int ks = 0; ks < 2; ++ks) {
                const bf16x8 pa = *(const bf16x8*)&QPs[w * 16 + l15][ks * 32 + lhi * 8];
                const bf16x8 vb = *(const bf16x8*)&Vts[n * 16 + l15][ks * 32 + lhi * 8];
                o_frag[n] = __builtin_amdgcn_mfma_f32_16x16x32_bf16(pa, vb, o_frag[n], 0, 0, 0);
            }
        }
    }

    // ---- epilogue: unnormalized bf16 partial + (m,l) per row ----
    #pragma unroll
    for (int i = 0; i < 4; ++i) {
        const int r  = w * 16 + lhi * 4 + i;
        const int rg = qb + r;
        if (rg < NTOK) {
            ushort_t* op = part + ((long)b * NTOK + rg) * DMODEL + h * 64 + l15;
            #pragma unroll
            for (int n = 0; n < 4; ++n) op[n * 16] = f2bf(o_frag[n][i]);
            if (l15 == 0)
                ml[(((long)split * B_SZ + b) * NHEAD + h) * (NQT * 64) + (long)qt * 64 + r]
                    = make_float2(m_run[i], l_run[i]);
        }
    }
}

// ---------------- combine the two KV-splits (in place into part0) ----------------
__global__ __launch_bounds__(256)
void k_comb(ushort_t* __restrict__ part0, const ushort_t* __restrict__ part1,
            const float2* __restrict__ ml)
{
    const int qt = blockIdx.x, h = blockIdx.y, b = blockIdx.z;
    const int t  = threadIdx.x;
    const int r  = t >> 2;
    const int c0 = (t & 3) * 16;
    const int rg = qt * 64 + r;
    if (rg >= NTOK) return;
    const long mli = ((long)b * NHEAD + h) * (NQT * 64) + (long)qt * 64 + r;
    const float2 a0 = ml[mli];
    const float2 a1 = ml[(long)B_SZ * NHEAD * NQT * 64 + mli];
    const float M  = fmaxf(a0.x, a1.x);
    const float e0 = exp2f(a0.x - M);
    const float e1 = exp2f(a1.x - M);
    const float inv = 1.f / (a0.y * e0 + a1.y * e1);
    ushort_t*       p0 = part0 + ((long)b * NTOK + rg) * DMODEL + h * 64 + c0;
    const ushort_t* p1 = part1 + ((long)b * NTOK + rg) * DMODEL + h * 64 + c0;
    #pragma unroll
    for (int c = 0; c < 16; ++c)
        p0[c] = f2bf((bf2f(p0[c]) * e0 + bf2f(p1[c]) * e1) * inv);
}

// ---------------- layer-2 decode attention: 1 query (cls) per (h,b) ----------------
__global__ __launch_bounds__(256)
void k_attn1(const ushort_t* __restrict__ qkvb, const float* __restrict__ mems,
             const float* __restrict__ pos, ushort_t* __restrict__ outp)
{
    __shared__ float sarr[KLEN];
    __shared__ float red[4];
    __shared__ float osum[4][64];
    const int h = blockIdx.x, b = blockIdx.y;
    const int t = threadIdx.x;
    const int w = t >> 6;

    // q (cls row) into registers
    const ushort_t* qrow = qkvb + (long)b * NTOK * 1536 + h * 64;
    float q[64];
    #pragma unroll
    for (int d = 0; d < 64; ++d) q[d] = bf2f(qrow[d]);

    // phase 1: scores (K from qkv/mems + pos); CSCALE has log2(e) folded -> exp2
    float sreg[17];
    float lmax = NEG_BIG;
    #pragma unroll
    for (int it = 0; it < 17; ++it) {
        const int j = t + it * 256;
        if (j < KLEN) {
            float s = 0.f;
            if (j < NTOK) {
                const ushort_t* kr = qkvb + ((long)b * NTOK + j) * 1536 + 512 + h * 64;
                const float* pp = pos + (long)j * DMODEL + h * 64;
                #pragma unroll
                for (int d = 0; d < 64; ++d) s += q[d] * (bf2f(kr[d]) + pp[d]);
            } else {
                const float* mb = mems + (((long)B_SZ + b) * MEMLEN + (j - NTOK)) * DMODEL + h * 64;
                const float* pp = pos + (long)j * DMODEL + h * 64;
                #pragma unroll
                for (int d = 0; d < 64; ++d) s += q[d] * (mb[d] + pp[d]);
            }
            s *= CSCALE;
            sreg[it] = s;
            lmax = fmaxf(lmax, s);
        } else sreg[it] = NEG_BIG;
    }
    #pragma unroll
    for (int m = 1; m < 64; m <<= 1) lmax = fmaxf(lmax, __shfl_xor(lmax, m));
    if ((t & 63) == 0) red[w] = lmax;
    __syncthreads();
    const float M = fmaxf(fmaxf(red[0], red[1]), fmaxf(red[2], red[3]));
    __syncthreads();

    float lsum = 0.f;
    #pragma unroll
    for (int it = 0; it < 17; ++it) {
        const int j = t + it * 256;
        if (j < KLEN) {
            const float pp = exp2f(sreg[it] - M);
            sarr[j] = pp;
            lsum += pp;
        }
    }
    #pragma unroll
    for (int m = 1; m < 64; m <<= 1) lsum += __shfl_xor(lsum, m);
    if ((t & 63) == 0) red[w] = lsum;
    __syncthreads();
    const float L = red[0] + red[1] + red[2] + red[3];
    __syncthreads();

    // phase 2: o[d] = sum_j p_j * v[j][d]
    const int d = t & 63, g = t >> 6;
    float o = 0.f;
    for (int j = g; j < KLEN; j += 4) {
        float v;
        if (j < NTOK) v = bf2f(qkvb[((long)b * NTOK + j) * 1536 + 1024 + h * 64 + d]);
        else          v = mems[(((long)B_SZ + b) * MEMLEN + (j - NTOK)) * DMODEL + h * 64 + d];
        v += pos[(long)j * DMODEL + h * 64 + d];
        o += sarr[j] * v;
    }
    osum[g][d] = o;
    __syncthreads();
    if (t < 64) {
        const float r = (osum[0][t] + osum[1][t] + osum[2][t] + osum[3][t]) / L;
        outp[(long)b * NTOK * DMODEL + h * 64 + t] = f2bf(r);
    }
}

// ---------------- final LN + 2-class head on cls row ----------------
__global__ __launch_bounds__(256)
void k_final(const float* __restrict__ x, const float* __restrict__ g,
             const float* __restrict__ bb, const float* __restrict__ w2,
             const float* __restrict__ b2, float* __restrict__ out)
{
    __shared__ float sh[4];
    const int b = blockIdx.x;
    const float* xr = x + (long)b * NTOK * DMODEL;
    const int t = threadIdx.x;
    const float v0 = xr[t], v1 = xr[t + 256];
    const float s  = block_reduce_sum_256(v0 + v1, sh);
    const float s2 = block_reduce_sum_256(v0 * v0 + v1 * v1, sh);
    const float mu = s * (1.f / DMODEL);
    const float var = s2 * (1.f / DMODEL) - mu * mu;
    const float rs = rsqrtf(var + 1e-5f);
    const float n0 = (v0 - mu) * rs * g[t] + bb[t];
    const float n1 = (v1 - mu) * rs * g[t + 256] + bb[t + 256];
    const float p0 = block_reduce_sum_256(n0 * w2[t * 2 + 0] + n1 * w2[(t + 256) * 2 + 0], sh);
    const float p1 = block_reduce_sum_256(n0 * w2[t * 2 + 1] + n1 * w2[(t + 256) * 2 + 1], sh);
    if (t == 0) {
        out[b * 2 + 0] = p0 + b2[0];
        out[b * 2 + 1] = p1 + b2[1];
    }
}

// ---------------- host orchestration ----------------
extern "C" void kernel_launch(void* const* d_in, const int* in_sizes, int n_in,
                              void* d_out, int out_size, void* d_ws, size_t ws_size,
                              hipStream_t stream)
{
    const float* data    = (const float*)d_in[0];
    const float* mems    = (const float*)d_in[1];
    const float* fc1_w   = (const float*)d_in[2];
    const float* fc1_b   = (const float*)d_in[3];
    const float* cls     = (const float*)d_in[4];
    const float* ln1_g   = (const float*)d_in[5];
    const float* ln1_b   = (const float*)d_in[6];
    const float* qkv_w   = (const float*)d_in[7];
    const float* out_w   = (const float*)d_in[8];
    const float* out_b   = (const float*)d_in[9];
    const float* ln2_g   = (const float*)d_in[10];
    const float* ln2_b   = (const float*)d_in[11];
    const float* ff_w1   = (const float*)d_in[12];
    const float* ff_b1   = (const float*)d_in[13];
    const float* ff_w2   = (const float*)d_in[14];
    const float* ff_b2   = (const float*)d_in[15];
    const float* normf_g = (const float*)d_in[16];
    const float* normf_b = (const float*)d_in[17];
    const float* fc2_w   = (const float*)d_in[18];
    const float* fc2_b   = (const float*)d_in[19];
    float* out = (float*)d_out;

    const int MROWS = B_SZ * NTOK;                          // 8194
    const int MT128 = (MROWS + 127) / 128;                  // 65
    const long XROW = (long)NTOK * DMODEL;                  // batch stride in x

    // ---- workspace layout ----
    char* p = (char*)d_ws;
    float* x   = (float*)p;            p += (long)B_SZ * NTOK * DMODEL * 4;
    float* pos = (float*)p;            p += (long)KLEN * DMODEL * 4;
    ushort_t* data_bf = (ushort_t*)p;  p += (long)B_SZ * 4096 * INDIM * 2;    // dead post-fc1 -> attn partials
    ushort_t* actA    = (ushort_t*)p;  p += (long)MROWS * DMODEL * 2;
    ushort_t* actB    = (ushort_t*)p;  p += (long)MROWS * DMODEL * 2;
    ushort_t* fc1_wt  = (ushort_t*)p;  p += (long)DMODEL * INDIM * 2;
    ushort_t* qkv_wt  = (ushort_t*)p;  p += (long)2 * 1536 * DMODEL * 2;
    ushort_t* out_wt  = (ushort_t*)p;  p += (long)2 * DMODEL * DMODEL * 2;
    ushort_t* ff1_wt  = (ushort_t*)p;  p += (long)2 * MLPD * DMODEL * 2;
    ushort_t* ff2_wt  = (ushort_t*)p;  p += (long)2 * DMODEL * MLPD * 2;
    ushort_t* qkv_bf  = (ushort_t*)p;                                   // [8194][1536]
    ushort_t* kf      = qkv_bf + (long)MROWS * 1536;                    // [2][4105][512]
    ushort_t* vt      = kf + (long)B_SZ * KLEN * DMODEL;                // [16][64][4160]
    ushort_t* ffbuf   = qkv_bf;                                         // overlays

    // attn partial overlays (data_bf is dead after fc1)
    ushort_t* part1 = data_bf;                                          // [B][NTOK][512] bf16
    float2*   mlbuf = (float2*)(data_bf + (long)B_SZ * NTOK * DMODEL);  // [2][B][8][65*64]

    // ---- one-time converts ----
    k_f2b<<<dim3(2048), dim3(256), 0, stream>>>(data, data_bf, (long)B_SZ * 4096 * INDIM / 4);
    k_w2bt<<<dim3(DMODEL/64, INDIM/64, 1),  dim3(256), 0, stream>>>(fc1_w, fc1_wt, INDIM, DMODEL);
    k_w2bt<<<dim3(1536/64, DMODEL/64, 2),   dim3(256), 0, stream>>>(qkv_w, qkv_wt, DMODEL, 1536);
    k_w2bt<<<dim3(DMODEL/64, DMODEL/64, 2), dim3(256), 0, stream>>>(out_w, out_wt, DMODEL, DMODEL);
    k_w2bt<<<dim3(MLPD/64, DMODEL/64, 2),   dim3(256), 0, stream>>>(ff_w1, ff1_wt, DMODEL, MLPD);
    k_w2bt<<<dim3(DMODEL/64, MLPD/64, 2),   dim3(256), 0, stream>>>(ff_w2, ff2_wt, MLPD, DMODEL);

    k_pos<<<dim3(KLEN), dim3(256), 0, stream>>>(pos);
    k_cls<<<dim3(B_SZ), dim3(512), 0, stream>>>(cls, x);

    // fc1 + ReLU -> x rows 1..4096 per batch (fp32 out)
    k_gemm_bf<EPI_BIAS_RELU, 0><<<dim3(DMODEL/128, 4096/128, B_SZ), dim3(256), 0, stream>>>(
        data_bf, fc1_wt, fc1_b, x + DMODEL, 4096, INDIM, DMODEL, DMODEL,
        (long)4096 * INDIM, XROW);

    const int KBK = (KLEN * 128 + 255) / 256;

    // ================= layer 0 (full) =================
    {
        k_ln<<<dim3(MROWS), dim3(256), 0, stream>>>(x, actA, ln1_g, ln1_b, 1);
        k_gemm_bf<EPI_NONE, 1><<<dim3(1536/128, MT128, 1), dim3(256), 0, stream>>>(
            actA, qkv_wt, nullptr, qkv_bf, MROWS, DMODEL, 1536, 1536, 0, 0);
        k_build_k <<<dim3(KBK, B_SZ), dim3(256), 0, stream>>>(qkv_bf, mems, pos, kf, 0);
        k_build_vt<<<dim3(KLEN_PAD/64, B_SZ, NHEAD), dim3(256), 0, stream>>>(qkv_bf, mems, pos, vt, 0);
        k_attn_sp<<<dim3(NQT, 16, B_SZ), dim3(256), 0, stream>>>(qkv_bf, kf, vt, actB, part1, mlbuf);
        k_comb   <<<dim3(NQT, NHEAD, B_SZ), dim3(256), 0, stream>>>(actB, part1, mlbuf);
        k_gemm_bf<EPI_BIAS_RES, 0><<<dim3(DMODEL/128, MT128, 1), dim3(256), 0, stream>>>(
            actB, out_wt, out_b, x, MROWS, DMODEL, DMODEL, DMODEL, 0, 0);
        k_ln<<<dim3(MROWS), dim3(256), 0, stream>>>(x, actA, ln2_g, ln2_b, 1);
        k_gemm_bf<EPI_BIAS_GELU, 1><<<dim3(MLPD/128, MT128, 1), dim3(256), 0, stream>>>(
            actA, ff1_wt, ff_b1, ffbuf, MROWS, DMODEL, MLPD, MLPD, 0, 0);
        k_gemm_bf<EPI_BIAS_RES, 0><<<dim3(DMODEL/128, MT128, 1), dim3(256), 0, stream>>>(
            ffbuf, ff2_wt, ff_b2, x, MROWS, MLPD, DMODEL, DMODEL, 0, 0);
    }

    // ================= layer 1 (only cls row feeds the head) =================
    {
        k_ln<<<dim3(MROWS), dim3(256), 0, stream>>>(x, actA, ln1_g + DMODEL, ln1_b + DMODEL, 1);
        // K,V columns for all rows (N=1024, cols 512..1535 of qkv)
        k_gemm_bf<EPI_NONE, 1><<<dim3(1024/128, MT128, 1), dim3(256), 0, stream>>>(
            actA, qkv_wt + (long)1536 * DMODEL + (long)512 * DMODEL, nullptr, qkv_bf + 512,
            MROWS, DMODEL, 1024, 1536, 0, 0);
        // Q for cls row only
        k_gemv<EPI_NONE, 1><<<dim3(512/64, B_SZ), dim3(256), 0, stream>>>(
            actA, qkv_wt + (long)1536 * DMODEL, nullptr, qkv_bf,
            DMODEL, 512, (long)NTOK * DMODEL, (long)NTOK * 1536);
        // decode attention straight from qkv_bf (+mems +pos)
        k_attn1<<<dim3(NHEAD, B_SZ), dim3(256), 0, stream>>>(qkv_bf, mems, pos, actB);
        // out-proj + ff on cls row per batch
        k_gemv<EPI_BIAS_RES, 0><<<dim3(512/64, B_SZ), dim3(256), 0, stream>>>(
            actB, out_wt + (long)DMODEL * DMODEL, out_b + DMODEL, x,
            DMODEL, 512, (long)NTOK * DMODEL, XROW);
        k_ln<<<dim3(B_SZ), dim3(256), 0, stream>>>(x, actA, ln2_g + DMODEL, ln2_b + DMODEL, NTOK);
        k_gemv<EPI_BIAS_GELU, 1><<<dim3(MLPD/64, B_SZ), dim3(256), 0, stream>>>(
            actA, ff1_wt + (long)MLPD * DMODEL, ff_b1 + MLPD, ffbuf,
            DMODEL, MLPD, (long)NTOK * DMODEL, MLPD);
        k_gemv<EPI_BIAS_RES, 0><<<dim3(512/64, B_SZ), dim3(256), 0, stream>>>(
            ffbuf, ff2_wt + (long)DMODEL * MLPD, ff_b2 + DMODEL, x,
            MLPD, 512, MLPD, XROW);
    }

    k_final<<<dim3(B_SZ), dim3(256), 0, stream>>>(x, normf_g, normf_b, fc2_w, fc2_b, out);
}

// Round 9
// 746.536 us; speedup vs baseline: 1.6649x; 1.6649x over previous
//
#include <hip/hip_runtime.h>
#include <hip/hip_bf16.h>
#include <math.h>

// ---------------- problem constants ----------------
#define B_SZ   2
#define NTOK   4097      // n = 4096 + cls
#define KLEN   4105      // n + mem_len(8)
#define KLEN_PAD 4160    // 65 * 64
#define DMODEL 512
#define INDIM  1024
#define NHEAD  8
#define DHEAD  64
#define MLPD   2048
#define MEMLEN 8
#define NEG_BIG  -1.0e30f
#define CSCALE 0.18033688f   // (1/sqrt(64)) * log2(e); softmax runs in log2 domain
#define NQT 65               // q-tiles of 64
#define SPLIT_MID 33         // split0: tiles [0,33), split1: [33,65)
#define NSPLIT1 17           // layer-2 decode: key chunks of 256
#define CH1 256

typedef unsigned short ushort_t;
typedef short bf16x8 __attribute__((ext_vector_type(8)));
typedef float f32x4  __attribute__((ext_vector_type(4)));

__device__ __forceinline__ unsigned short f2bf(float f) {
    union { float f; unsigned u; } v; v.f = f;
    const unsigned r = v.u + 0x7fff + ((v.u >> 16) & 1);   // RTNE
    return (unsigned short)(r >> 16);
}
__device__ __forceinline__ unsigned short f2bf_rhu(float f) {   // cheap round (P in [0,1])
    union { float f; unsigned u; } v; v.f = f;
    return (unsigned short)((v.u + 0x8000u) >> 16);
}
__device__ __forceinline__ float bf2f(unsigned short u) {
    union { unsigned u; float f; } v; v.u = ((unsigned)u) << 16;
    return v.f;
}

// async global->LDS, 16B per lane; lds base must be wave-uniform
__device__ __forceinline__ void gload_lds16(const void* g, void* l) {
    __builtin_amdgcn_global_load_lds(
        (const __attribute__((address_space(1))) unsigned int*)g,
        (__attribute__((address_space(3))) unsigned int*)l, 16, 0, 0);
}

// ---------------- small helpers ----------------
__device__ __forceinline__ float block_reduce_sum_256(float v, float* sh) {
    #pragma unroll
    for (int m = 1; m < 64; m <<= 1) v += __shfl_xor(v, m);
    const int w = threadIdx.x >> 6;
    if ((threadIdx.x & 63) == 0) sh[w] = v;
    __syncthreads();
    float r = sh[0] + sh[1] + sh[2] + sh[3];
    __syncthreads();
    return r;
}

// ---------------- pos emb (fast trig) ----------------
__global__ void k_pos(float* __restrict__ pos) {
    const int p = blockIdx.x;
    const int j = threadIdx.x;
    const float position = (float)(KLEN - 1 - p);
    const float inv_freq = exp2f(-(float)j * 0.051905126f);   // 10000^(-j/256)
    const float x = position * inv_freq;
    pos[(long)p * DMODEL + j]       = __sinf(x);
    pos[(long)p * DMODEL + 256 + j] = __cosf(x);
}

// ---------------- cls token ----------------
__global__ void k_cls(const float* __restrict__ cls, float* __restrict__ x) {
    const int b = blockIdx.x;
    x[(long)b * NTOK * DMODEL + threadIdx.x] = cls[threadIdx.x];
}

// ---------------- fp32 -> bf16 convert ----------------
__global__ __launch_bounds__(256)
void k_f2b(const float* __restrict__ in, ushort_t* __restrict__ out, long n4) {
    for (long i = blockIdx.x * 256 + threadIdx.x; i < n4; i += (long)gridDim.x * 256) {
        const float4 f = ((const float4*)in)[i];
        ushort4 u;
        u.x = f2bf(f.x); u.y = f2bf(f.y); u.z = f2bf(f.z); u.w = f2bf(f.w);
        ((ushort4*)out)[i] = u;
    }
}

// ---------------- weight fp32[K][N] -> bf16 Wt[N][K] ----------------
__global__ __launch_bounds__(256)
void k_w2bt(const float* __restrict__ W, ushort_t* __restrict__ Wt, int K, int N) {
    __shared__ float tile[64][65];
    W  += (long)blockIdx.z * K * N;
    Wt += (long)blockIdx.z * N * K;
    const int n0 = blockIdx.x * 64, k0 = blockIdx.y * 64;
    const int t = threadIdx.x;
    #pragma unroll
    for (int rep = 0; rep < 16; ++rep) {
        const int idx = rep * 256 + t;
        const int r = idx >> 6, c = idx & 63;
        tile[r][c] = W[(long)(k0 + r) * N + n0 + c];
    }
    __syncthreads();
    #pragma unroll
    for (int rep = 0; rep < 16; ++rep) {
        const int idx = rep * 256 + t;
        const int n = idx >> 6, kk = idx & 63;
        Wt[(long)(n0 + n) * K + k0 + kk] = f2bf(tile[kk][n]);
    }
}

// ---------------- bf16 MFMA GEMM ----------------
enum { EPI_NONE = 0, EPI_BIAS_RELU = 1, EPI_BIAS_GELU = 2, EPI_BIAS_RES = 3 };

template <int EPI, int OBF16>
__global__ __launch_bounds__(256)
void k_gemm_bf(const ushort_t* __restrict__ A, const ushort_t* __restrict__ Wt,
               const float* __restrict__ bias, void* __restrict__ Cv,
               int M, int K, int N, long ldc, long sAb, long sCb)
{
    __shared__ ushort_t As[128 * 64];
    __shared__ ushort_t Bs[128 * 64];
    const int t    = threadIdx.x;
    const int lane = t & 63;
    const int w    = t >> 6;
    const int l15  = lane & 15;
    const int lhi  = lane >> 4;
    const int wr   = w >> 1, wc = w & 1;
    const long bm = (long)blockIdx.y * 128, bn = (long)blockIdx.x * 128;
    A += (long)blockIdx.z * sAb;
    float*    Cf = (float*)Cv    + (long)blockIdx.z * sCb;
    ushort_t* Cb = (ushort_t*)Cv + (long)blockIdx.z * sCb;

    int srow[4], scol[4];
    #pragma unroll
    for (int i = 0; i < 4; ++i) {
        const int c = i * 256 + t;
        srow[i] = c >> 3;
        scol[i] = ((c & 7) ^ (srow[i] & 7)) << 3;
    }

    f32x4 acc[4][4] = {};

    for (int k0 = 0; k0 < K; k0 += 64) {
        __syncthreads();
        #pragma unroll
        for (int i = 0; i < 4; ++i) {
            long ar = bm + srow[i]; if (ar >= M) ar = M - 1;
            gload_lds16(A + ar * (long)K + k0 + scol[i],
                        &As[(i * 256 + (t & ~63)) * 8]);
        }
        #pragma unroll
        for (int i = 0; i < 4; ++i) {
            gload_lds16(Wt + (bn + srow[i]) * (long)K + k0 + scol[i],
                        &Bs[(i * 256 + (t & ~63)) * 8]);
        }
        asm volatile("s_waitcnt vmcnt(0)" ::: "memory");
        __syncthreads();

        #pragma unroll
        for (int ks = 0; ks < 2; ++ks) {
            bf16x8 af[4], bfr[4];
            #pragma unroll
            for (int m = 0; m < 4; ++m) {
                const int row = wr * 64 + m * 16 + l15;
                const int cb  = (ks * 64 + lhi * 16) ^ ((row & 7) << 4);
                af[m] = *(const bf16x8*)((const char*)As + row * 128 + cb);
            }
            #pragma unroll
            for (int n = 0; n < 4; ++n) {
                const int row = wc * 64 + n * 16 + l15;
                const int cb  = (ks * 64 + lhi * 16) ^ ((row & 7) << 4);
                bfr[n] = *(const bf16x8*)((const char*)Bs + row * 128 + cb);
            }
            #pragma unroll
            for (int m = 0; m < 4; ++m)
                #pragma unroll
                for (int n = 0; n < 4; ++n)
                    acc[m][n] = __builtin_amdgcn_mfma_f32_16x16x32_bf16(af[m], bfr[n], acc[m][n], 0, 0, 0);
        }
    }

    #pragma unroll
    for (int m = 0; m < 4; ++m) {
        #pragma unroll
        for (int j = 0; j < 4; ++j) {
            const long mg = bm + wr * 64 + m * 16 + lhi * 4 + j;
            if (mg < M) {
                #pragma unroll
                for (int n = 0; n < 4; ++n) {
                    const long ng = bn + wc * 64 + n * 16 + l15;
                    float r = acc[m][n][j];
                    if (EPI != EPI_NONE) r += bias[ng];
                    if (EPI == EPI_BIAS_RELU) r = fmaxf(r, 0.f);
                    if (EPI == EPI_BIAS_GELU) r = 0.5f * r * (1.f + erff(r * 0.70710678118654752f));
                    if (OBF16) Cb[mg * ldc + ng] = f2bf(r);
                    else if (EPI == EPI_BIAS_RES) Cf[mg * ldc + ng] += r;
                    else Cf[mg * ldc + ng] = r;
                }
            }
        }
    }
}

// ---------------- GEMV (M=1 per batch) ----------------
template <int EPI, int OBF16>
__global__ __launch_bounds__(256)
void k_gemv(const ushort_t* __restrict__ A, const ushort_t* __restrict__ Wt,
            const float* __restrict__ bias, void* __restrict__ Cv,
            int K, int N, long sA, long sC)
{
    const int b = blockIdx.y;
    const int n = blockIdx.x * 64 + (threadIdx.x >> 2);
    const int j = threadIdx.x & 3;
    const ushort_t* a = A + (long)b * sA;
    const ushort_t* wv = Wt + (long)n * K;
    float sum = 0.f;
    for (int k0 = j * 8; k0 < K; k0 += 32) {
        const bf16x8 av = *(const bf16x8*)(a + k0);
        const bf16x8 wr = *(const bf16x8*)(wv + k0);
        #pragma unroll
        for (int e = 0; e < 8; ++e)
            sum += bf2f((ushort_t)av[e]) * bf2f((ushort_t)wr[e]);
    }
    sum += __shfl_xor(sum, 1);
    sum += __shfl_xor(sum, 2);
    if (j == 0 && n < N) {
        float r = sum;
        if (EPI != EPI_NONE) r += bias[n];
        if (EPI == EPI_BIAS_GELU) r = 0.5f * r * (1.f + erff(r * 0.70710678118654752f));
        if (OBF16) ((ushort_t*)Cv)[(long)b * sC + n] = f2bf(r);
        else if (EPI == EPI_BIAS_RES) ((float*)Cv)[(long)b * sC + n] += r;
        else ((float*)Cv)[(long)b * sC + n] = r;
    }
}

// ---------------- LayerNorm, bf16 out ----------------
__global__ __launch_bounds__(256)
void k_ln(const float* __restrict__ x, ushort_t* __restrict__ y,
          const float* __restrict__ g, const float* __restrict__ b, long rstride)
{
    __shared__ float sh[4];
    const long row = (long)blockIdx.x * rstride;
    const float* xr = x + row * DMODEL;
    const int t = threadIdx.x;
    const float v0 = xr[t], v1 = xr[t + 256];
    const float s  = block_reduce_sum_256(v0 + v1, sh);
    const float s2 = block_reduce_sum_256(v0 * v0 + v1 * v1, sh);
    const float mu = s * (1.f / DMODEL);
    const float var = s2 * (1.f / DMODEL) - mu * mu;
    const float rs = rsqrtf(var + 1e-5f);
    y[row * DMODEL + t]       = f2bf((v0 - mu) * rs * g[t] + b[t]);
    y[row * DMODEL + t + 256] = f2bf((v1 - mu) * rs * g[t + 256] + b[t + 256]);
}

// ---------------- build bf16 K rows (pre-scaled by CSCALE): [b][klen][512] ----------------
__global__ __launch_bounds__(256)
void k_build_k(const ushort_t* __restrict__ qkvb, const float* __restrict__ mems,
               const float* __restrict__ pos, ushort_t* __restrict__ kf, int layer)
{
    const int b = blockIdx.y;
    const long idx = (long)blockIdx.x * 256 + threadIdx.x;   // over KLEN*128
    const int j  = (int)(idx >> 7);
    const int d0 = (int)(idx & 127) * 4;
    if (j >= KLEN) return;
    float v0, v1, v2, v3;
    if (j < NTOK) {
        const ushort_t* s = qkvb + ((long)b * NTOK + j) * 1536 + 512 + d0;
        v0 = bf2f(s[0]); v1 = bf2f(s[1]); v2 = bf2f(s[2]); v3 = bf2f(s[3]);
    } else {
        const float* mb = mems + (((long)layer * B_SZ + b) * MEMLEN + (j - NTOK)) * DMODEL + d0;
        v0 = mb[0]; v1 = mb[1]; v2 = mb[2]; v3 = mb[3];
    }
    const float4 pe = *(const float4*)(pos + (long)j * DMODEL + d0);
    ushort4 o;
    o.x = f2bf((v0 + pe.x) * CSCALE);
    o.y = f2bf((v1 + pe.y) * CSCALE);
    o.z = f2bf((v2 + pe.z) * CSCALE);
    o.w = f2bf((v3 + pe.w) * CSCALE);
    *(ushort4*)(kf + ((long)b * KLEN + j) * DMODEL + d0) = o;
}

// ---------------- build bf16 V transposed: [b*8+h][d=64][KLEN_PAD] ----------------
__global__ __launch_bounds__(256)
void k_build_vt(const ushort_t* __restrict__ qkvb, const float* __restrict__ mems,
                const float* __restrict__ pos, ushort_t* __restrict__ vt, int layer)
{
    __shared__ ushort_t tile[64][65];
    const int jb = blockIdx.x * 64;
    const int b  = blockIdx.y;
    const int h  = blockIdx.z;
    const int t  = threadIdx.x;
    #pragma unroll
    for (int rep = 0; rep < 16; ++rep) {
        const int idx = rep * 256 + t;
        const int r = idx >> 6, c = idx & 63;
        const int j = jb + r;
        float val = 0.f;
        if (j < NTOK)
            val = bf2f(qkvb[((long)b * NTOK + j) * 1536 + 1024 + h * 64 + c]) + pos[(long)j * DMODEL + h * 64 + c];
        else if (j < KLEN)
            val = mems[(((long)layer * B_SZ + b) * MEMLEN + (j - NTOK)) * DMODEL + h * 64 + c]
                + pos[(long)j * DMODEL + h * 64 + c];
        tile[c][r] = f2bf(val);
    }
    __syncthreads();
    #pragma unroll
    for (int rep = 0; rep < 16; ++rep) {
        const int idx = rep * 256 + t;
        const int d = idx >> 6, r = idx & 63;
        vt[(((long)b * NHEAD + h) * 64 + d) * (long)KLEN_PAD + jb + r] = tile[d][r];
    }
}

// ---------------- MFMA flash attention, KV-split=2, partial outputs ----------------
// grid: (NQT, 16, B_SZ); blockIdx.y = split*8 + h.
#define LDSP 72

__global__ __launch_bounds__(256)
void k_attn_sp(const ushort_t* __restrict__ qkvb,
               const ushort_t* __restrict__ kf,
               const ushort_t* __restrict__ vt,
               ushort_t* __restrict__ part0,
               ushort_t* __restrict__ part1,
               float2* __restrict__ ml)
{
    __shared__ ushort_t QPs[64][LDSP];  // Q at start, then reused as P
    __shared__ ushort_t Ks [64][LDSP];
    __shared__ ushort_t Vts[64][LDSP];

    const int t     = threadIdx.x;
    const int lane  = t & 63;
    const int w     = t >> 6;
    const int l15   = lane & 15;
    const int lhi   = lane >> 4;
    const int qt    = blockIdx.x;
    const int qb    = qt * 64;
    const int split = blockIdx.y >> 3;
    const int h     = blockIdx.y & 7;
    const int b     = blockIdx.z;
    const int ktBeg = split ? SPLIT_MID : 0;
    const int ktEnd = split ? NQT : SPLIT_MID;
    ushort_t* part  = split ? part1 : part0;

    // ---- stage Q ----
    {
        const int r  = t >> 2;
        const int c0 = (t & 3) * 16;
        const int qg = qb + r;
        uint4 u0 = make_uint4(0,0,0,0), u1 = make_uint4(0,0,0,0);
        if (qg < NTOK) {
            const ushort_t* src = qkvb + ((long)b * NTOK + qg) * 1536 + h * 64 + c0;
            u0 = ((const uint4*)src)[0];
            u1 = ((const uint4*)src)[1];
        }
        *(uint4*)&QPs[r][c0]     = u0;
        *(uint4*)&QPs[r][c0 + 8] = u1;
    }
    __syncthreads();
    bf16x8 q_frag[2];
    #pragma unroll
    for (int ks = 0; ks < 2; ++ks)
        q_frag[ks] = *(const bf16x8*)&QPs[w * 16 + l15][ks * 32 + lhi * 8];

    f32x4 o_frag[4] = {};
    float m_run[4] = {NEG_BIG, NEG_BIG, NEG_BIG, NEG_BIG};
    float l_run[4] = {0.f, 0.f, 0.f, 0.f};

    const ushort_t* kbase = kf + (long)b * KLEN * DMODEL + h * 64;
    const ushort_t* vbase = vt + ((long)b * NHEAD + h) * 64 * (long)KLEN_PAD;

    for (int kt = ktBeg; kt < ktEnd; ++kt) {
        const int kb = kt * 64;
        __syncthreads();   // prev tile fully consumed
        {
            const int r = t >> 2;
            const int jg = kb + r;
            #pragma unroll
            for (int cc = 0; cc < 2; ++cc) {
                const int c8 = (t & 3) * 2 + cc;
                uint4 kv = make_uint4(0u, 0u, 0u, 0u);
                if (jg < KLEN) kv = *(const uint4*)(kbase + (long)jg * DMODEL + c8 * 8);
                *(uint4*)&Ks[r][c8 * 8] = kv;
                const uint4 vv = *(const uint4*)(vbase + (long)r * KLEN_PAD + kb + c8 * 8);
                *(uint4*)&Vts[r][c8 * 8] = vv;
            }
        }
        __syncthreads();

        // ---- S = Q @ K^T (log2 domain; scale folded into K) ----
        f32x4 s_frag[4];
        #pragma unroll
        for (int n = 0; n < 4; ++n) {
            f32x4 acc = {0.f, 0.f, 0.f, 0.f};
            #pragma unroll
            for (int ks = 0; ks < 2; ++ks) {
                const bf16x8 kfr = *(const bf16x8*)&Ks[n * 16 + l15][ks * 32 + lhi * 8];
                acc = __builtin_amdgcn_mfma_f32_16x16x32_bf16(q_frag[ks], kfr, acc, 0, 0, 0);
            }
            s_frag[n] = acc;
        }

        // ---- online softmax (exp2); mask only in global tail tile ----
        #pragma unroll
        for (int i = 0; i < 4; ++i) {
            float sv[4];
            #pragma unroll
            for (int n = 0; n < 4; ++n) sv[n] = s_frag[n][i];
            if (kt == NQT - 1) {
                #pragma unroll
                for (int n = 0; n < 4; ++n)
                    if (kb + n * 16 + l15 >= KLEN) sv[n] = NEG_BIG;
            }
            float mx = fmaxf(fmaxf(sv[0], sv[1]), fmaxf(sv[2], sv[3]));
            mx = fmaxf(mx, __shfl_xor(mx, 1));
            mx = fmaxf(mx, __shfl_xor(mx, 2));
            mx = fmaxf(mx, __shfl_xor(mx, 4));
            mx = fmaxf(mx, __shfl_xor(mx, 8));
            const float mnew  = fmaxf(m_run[i], mx);
            const float alpha = exp2f(m_run[i] - mnew);
            float lsum = 0.f;
            ushort_t pb[4];
            #pragma unroll
            for (int n = 0; n < 4; ++n) {
                const float p = exp2f(sv[n] - mnew);
                lsum += p;
                pb[n] = f2bf_rhu(p);
            }
            lsum += __shfl_xor(lsum, 1);
            lsum += __shfl_xor(lsum, 2);
            lsum += __shfl_xor(lsum, 4);
            lsum += __shfl_xor(lsum, 8);
            l_run[i] = l_run[i] * alpha + lsum;
            m_run[i] = mnew;
            #pragma unroll
            for (int n = 0; n < 4; ++n) {
                o_frag[n][i] *= alpha;
                QPs[w * 16 + lhi * 4 + i][n * 16 + l15] = pb[n];   // wave-private strip
            }
        }
        __syncthreads();   // P visible

        // ---- O += P @ V ----
        #pragma unroll
        for (int n = 0; n < 4; ++n) {
            #pragma unroll
            for (int ks = 0; ks < 2; ++ks) {
                const bf16x8 pa = *(const bf16x8*)&QPs[w * 16 + l15][ks * 32 + lhi * 8];
                const bf16x8 vb = *(const bf16x8*)&Vts[n * 16 + l15][ks * 32 + lhi * 8];
                o_frag[n] = __builtin_amdgcn_mfma_f32_16x16x32_bf16(pa, vb, o_frag[n], 0, 0, 0);
            }
        }
    }

    // ---- epilogue: unnormalized bf16 partial + (m,l) per row ----
    #pragma unroll
    for (int i = 0; i < 4; ++i) {
        const int r  = w * 16 + lhi * 4 + i;
        const int rg = qb + r;
        if (rg < NTOK) {
            ushort_t* op = part + ((long)b * NTOK + rg) * DMODEL + h * 64 + l15;
            #pragma unroll
            for (int n = 0; n < 4; ++n) op[n * 16] = f2bf(o_frag[n][i]);
            if (l15 == 0)
                ml[(((long)split * B_SZ + b) * NHEAD + h) * (NQT * 64) + (long)qt * 64 + r]
                    = make_float2(m_run[i], l_run[i]);
        }
    }
}

// ---------------- combine the two KV-splits (in place into part0) ----------------
__global__ __launch_bounds__(256)
void k_comb(ushort_t* __restrict__ part0, const ushort_t* __restrict__ part1,
            const float2* __restrict__ ml)
{
    const int qt = blockIdx.x, h = blockIdx.y, b = blockIdx.z;
    const int t  = threadIdx.x;
    const int r  = t >> 2;
    const int c0 = (t & 3) * 16;
    const int rg = qt * 64 + r;
    if (rg >= NTOK) return;
    const long mli = ((long)b * NHEAD + h) * (NQT * 64) + (long)qt * 64 + r;
    const float2 a0 = ml[mli];
    const float2 a1 = ml[(long)B_SZ * NHEAD * NQT * 64 + mli];
    const float M  = fmaxf(a0.x, a1.x);
    const float e0 = exp2f(a0.x - M);
    const float e1 = exp2f(a1.x - M);
    const float inv = 1.f / (a0.y * e0 + a1.y * e1);
    ushort_t*       p0 = part0 + ((long)b * NTOK + rg) * DMODEL + h * 64 + c0;
    const ushort_t* p1 = part1 + ((long)b * NTOK + rg) * DMODEL + h * 64 + c0;
    #pragma unroll
    for (int c = 0; c < 16; ++c)
        p0[c] = f2bf((bf2f(p0[c]) * e0 + bf2f(p1[c]) * e1) * inv);
}

// ---------------- layer-2 decode attention, split-K over 17 chunks of 256 keys ----------------
// grid (NSPLIT1, NHEAD, B_SZ); partial (m, l, o[64]) per block -> part[b][h][sp][66]
__global__ __launch_bounds__(256)
void k_attn1_sp(const ushort_t* __restrict__ qkvb, const float* __restrict__ mems,
                const float* __restrict__ pos, float* __restrict__ part)
{
    __shared__ float qs[64];
    __shared__ float sarr[CH1];
    __shared__ float red[4];
    __shared__ float osum[4][64];
    const int sp = blockIdx.x, h = blockIdx.y, b = blockIdx.z;
    const int t = threadIdx.x, w = t >> 6;
    const int j0 = sp * CH1;
    const int jend = min(j0 + CH1, KLEN);

    if (t < 64) qs[t] = bf2f(qkvb[(long)b * NTOK * 1536 + h * 64 + t]);
    __syncthreads();

    // ---- phase 1: one key per thread ----
    const int j = j0 + t;
    float s = NEG_BIG;
    if (j < KLEN) {
        float acc = 0.f;
        const float* pp = pos + (long)j * DMODEL + h * 64;
        if (j < NTOK) {
            const ushort_t* kr = qkvb + ((long)b * NTOK + j) * 1536 + 512 + h * 64;
            #pragma unroll
            for (int d = 0; d < 64; ++d) acc += qs[d] * (bf2f(kr[d]) + pp[d]);
        } else {
            const float* mb = mems + (((long)B_SZ + b) * MEMLEN + (j - NTOK)) * DMODEL + h * 64;
            #pragma unroll
            for (int d = 0; d < 64; ++d) acc += qs[d] * (mb[d] + pp[d]);
        }
        s = acc * CSCALE;
    }
    float mx = s;
    #pragma unroll
    for (int m = 1; m < 64; m <<= 1) mx = fmaxf(mx, __shfl_xor(mx, m));
    if ((t & 63) == 0) red[w] = mx;
    __syncthreads();
    const float M = fmaxf(fmaxf(red[0], red[1]), fmaxf(red[2], red[3]));
    __syncthreads();

    const float p = (j < KLEN) ? exp2f(s - M) : 0.f;
    sarr[t] = p;
    float lsum = p;
    #pragma unroll
    for (int m = 1; m < 64; m <<= 1) lsum += __shfl_xor(lsum, m);
    if ((t & 63) == 0) red[w] = lsum;
    __syncthreads();                       // red + sarr visible
    const float L = red[0] + red[1] + red[2] + red[3];

    // ---- phase 2: o[d] = sum_j p_j v[j][d] over this chunk ----
    const int d = t & 63, g = t >> 6;
    float o = 0.f;
    for (int j2 = j0 + g; j2 < jend; j2 += 4) {
        float v;
        if (j2 < NTOK) v = bf2f(qkvb[((long)b * NTOK + j2) * 1536 + 1024 + h * 64 + d]);
        else           v = mems[(((long)B_SZ + b) * MEMLEN + (j2 - NTOK)) * DMODEL + h * 64 + d];
        v += pos[(long)j2 * DMODEL + h * 64 + d];
        o += sarr[j2 - j0] * v;
    }
    osum[g][d] = o;
    __syncthreads();
    if (t < 64) {
        float* pb = part + (((long)b * NHEAD + h) * NSPLIT1 + sp) * 66;
        pb[2 + t] = osum[0][t] + osum[1][t] + osum[2][t] + osum[3][t];
        if (t == 0) { pb[0] = M; pb[1] = L; }
    }
}

// ---------------- combine decode chunks ----------------
__global__ __launch_bounds__(64)
void k_attn1_cb(const float* __restrict__ part, ushort_t* __restrict__ outp)
{
    const int h = blockIdx.x, b = blockIdx.y;
    const int t = threadIdx.x;   // 0..63
    const float* pb = part + ((long)b * NHEAD + h) * NSPLIT1 * 66;
    float M = NEG_BIG;
    #pragma unroll
    for (int c = 0; c < NSPLIT1; ++c) M = fmaxf(M, pb[c * 66]);
    float L = 0.f, o = 0.f;
    #pragma unroll
    for (int c = 0; c < NSPLIT1; ++c) {
        const float e = exp2f(pb[c * 66] - M);
        L += e * pb[c * 66 + 1];
        o += e * pb[c * 66 + 2 + t];
    }
    outp[(long)b * NTOK * DMODEL + h * 64 + t] = f2bf(o / L);
}

// ---------------- final LN + 2-class head on cls row ----------------
__global__ __launch_bounds__(256)
void k_final(const float* __restrict__ x, const float* __restrict__ g,
             const float* __restrict__ bb, const float* __restrict__ w2,
             const float* __restrict__ b2, float* __restrict__ out)
{
    __shared__ float sh[4];
    const int b = blockIdx.x;
    const float* xr = x + (long)b * NTOK * DMODEL;
    const int t = threadIdx.x;
    const float v0 = xr[t], v1 = xr[t + 256];
    const float s  = block_reduce_sum_256(v0 + v1, sh);
    const float s2 = block_reduce_sum_256(v0 * v0 + v1 * v1, sh);
    const float mu = s * (1.f / DMODEL);
    const float var = s2 * (1.f / DMODEL) - mu * mu;
    const float rs = rsqrtf(var + 1e-5f);
    const float n0 = (v0 - mu) * rs * g[t] + bb[t];
    const float n1 = (v1 - mu) * rs * g[t + 256] + bb[t + 256];
    const float p0 = block_reduce_sum_256(n0 * w2[t * 2 + 0] + n1 * w2[(t + 256) * 2 + 0], sh);
    const float p1 = block_reduce_sum_256(n0 * w2[t * 2 + 1] + n1 * w2[(t + 256) * 2 + 1], sh);
    if (t == 0) {
        out[b * 2 + 0] = p0 + b2[0];
        out[b * 2 + 1] = p1 + b2[1];
    }
}

// ---------------- host orchestration ----------------
extern "C" void kernel_launch(void* const* d_in, const int* in_sizes, int n_in,
                              void* d_out, int out_size, void* d_ws, size_t ws_size,
                              hipStream_t stream)
{
    const float* data    = (const float*)d_in[0];
    const float* mems    = (const float*)d_in[1];
    const float* fc1_w   = (const float*)d_in[2];
    const float* fc1_b   = (const float*)d_in[3];
    const float* cls     = (const float*)d_in[4];
    const float* ln1_g   = (const float*)d_in[5];
    const float* ln1_b   = (const float*)d_in[6];
    const float* qkv_w   = (const float*)d_in[7];
    const float* out_w   = (const float*)d_in[8];
    const float* out_b   = (const float*)d_in[9];
    const float* ln2_g   = (const float*)d_in[10];
    const float* ln2_b   = (const float*)d_in[11];
    const float* ff_w1   = (const float*)d_in[12];
    const float* ff_b1   = (const float*)d_in[13];
    const float* ff_w2   = (const float*)d_in[14];
    const float* ff_b2   = (const float*)d_in[15];
    const float* normf_g = (const float*)d_in[16];
    const float* normf_b = (const float*)d_in[17];
    const float* fc2_w   = (const float*)d_in[18];
    const float* fc2_b   = (const float*)d_in[19];
    float* out = (float*)d_out;

    const int MROWS = B_SZ * NTOK;                          // 8194
    const int MT128 = (MROWS + 127) / 128;                  // 65
    const long XROW = (long)NTOK * DMODEL;                  // batch stride in x

    // ---- workspace layout ----
    char* p = (char*)d_ws;
    float* x   = (float*)p;            p += (long)B_SZ * NTOK * DMODEL * 4;
    float* pos = (float*)p;            p += (long)KLEN * DMODEL * 4;
    ushort_t* data_bf = (ushort_t*)p;  p += (long)B_SZ * 4096 * INDIM * 2;    // dead post-fc1 -> attn partials
    ushort_t* actA    = (ushort_t*)p;  p += (long)MROWS * DMODEL * 2;
    ushort_t* actB    = (ushort_t*)p;  p += (long)MROWS * DMODEL * 2;
    ushort_t* fc1_wt  = (ushort_t*)p;  p += (long)DMODEL * INDIM * 2;
    ushort_t* qkv_wt  = (ushort_t*)p;  p += (long)2 * 1536 * DMODEL * 2;
    ushort_t* out_wt  = (ushort_t*)p;  p += (long)2 * DMODEL * DMODEL * 2;
    ushort_t* ff1_wt  = (ushort_t*)p;  p += (long)2 * MLPD * DMODEL * 2;
    ushort_t* ff2_wt  = (ushort_t*)p;  p += (long)2 * DMODEL * MLPD * 2;
    ushort_t* qkv_bf  = (ushort_t*)p;                                   // [8194][1536]
    ushort_t* kf      = qkv_bf + (long)MROWS * 1536;                    // [2][4105][512]
    ushort_t* vt      = kf + (long)B_SZ * KLEN * DMODEL;                // [16][64][4160]
    ushort_t* ffbuf   = qkv_bf;                                         // overlays

    // attn partial overlays (data_bf is dead after fc1)
    ushort_t* part1 = data_bf;                                          // [B][NTOK][512] bf16
    float2*   mlbuf = (float2*)(data_bf + (long)B_SZ * NTOK * DMODEL);  // [2][B][8][65*64]
    float*    dec_part = (float*)(mlbuf + (long)2 * B_SZ * NHEAD * NQT * 64); // [B][8][17][66]

    // ---- one-time converts ----
    k_f2b<<<dim3(2048), dim3(256), 0, stream>>>(data, data_bf, (long)B_SZ * 4096 * INDIM / 4);
    k_w2bt<<<dim3(DMODEL/64, INDIM/64, 1),  dim3(256), 0, stream>>>(fc1_w, fc1_wt, INDIM, DMODEL);
    k_w2bt<<<dim3(1536/64, DMODEL/64, 2),   dim3(256), 0, stream>>>(qkv_w, qkv_wt, DMODEL, 1536);
    k_w2bt<<<dim3(DMODEL/64, DMODEL/64, 2), dim3(256), 0, stream>>>(out_w, out_wt, DMODEL, DMODEL);
    k_w2bt<<<dim3(MLPD/64, DMODEL/64, 2),   dim3(256), 0, stream>>>(ff_w1, ff1_wt, DMODEL, MLPD);
    k_w2bt<<<dim3(DMODEL/64, MLPD/64, 2),   dim3(256), 0, stream>>>(ff_w2, ff2_wt, MLPD, DMODEL);

    k_pos<<<dim3(KLEN), dim3(256), 0, stream>>>(pos);
    k_cls<<<dim3(B_SZ), dim3(512), 0, stream>>>(cls, x);

    // fc1 + ReLU -> x rows 1..4096 per batch (fp32 out)
    k_gemm_bf<EPI_BIAS_RELU, 0><<<dim3(DMODEL/128, 4096/128, B_SZ), dim3(256), 0, stream>>>(
        data_bf, fc1_wt, fc1_b, x + DMODEL, 4096, INDIM, DMODEL, DMODEL,
        (long)4096 * INDIM, XROW);

    const int KBK = (KLEN * 128 + 255) / 256;

    // ================= layer 0 (full) =================
    {
        k_ln<<<dim3(MROWS), dim3(256), 0, stream>>>(x, actA, ln1_g, ln1_b, 1);
        k_gemm_bf<EPI_NONE, 1><<<dim3(1536/128, MT128, 1), dim3(256), 0, stream>>>(
            actA, qkv_wt, nullptr, qkv_bf, MROWS, DMODEL, 1536, 1536, 0, 0);
        k_build_k <<<dim3(KBK, B_SZ), dim3(256), 0, stream>>>(qkv_bf, mems, pos, kf, 0);
        k_build_vt<<<dim3(KLEN_PAD/64, B_SZ, NHEAD), dim3(256), 0, stream>>>(qkv_bf, mems, pos, vt, 0);
        k_attn_sp<<<dim3(NQT, 16, B_SZ), dim3(256), 0, stream>>>(qkv_bf, kf, vt, actB, part1, mlbuf);
        k_comb   <<<dim3(NQT, NHEAD, B_SZ), dim3(256), 0, stream>>>(actB, part1, mlbuf);
        k_gemm_bf<EPI_BIAS_RES, 0><<<dim3(DMODEL/128, MT128, 1), dim3(256), 0, stream>>>(
            actB, out_wt, out_b, x, MROWS, DMODEL, DMODEL, DMODEL, 0, 0);
        k_ln<<<dim3(MROWS), dim3(256), 0, stream>>>(x, actA, ln2_g, ln2_b, 1);
        k_gemm_bf<EPI_BIAS_GELU, 1><<<dim3(MLPD/128, MT128, 1), dim3(256), 0, stream>>>(
            actA, ff1_wt, ff_b1, ffbuf, MROWS, DMODEL, MLPD, MLPD, 0, 0);
        k_gemm_bf<EPI_BIAS_RES, 0><<<dim3(DMODEL/128, MT128, 1), dim3(256), 0, stream>>>(
            ffbuf, ff2_wt, ff_b2, x, MROWS, MLPD, DMODEL, DMODEL, 0, 0);
    }

    // ================= layer 1 (only cls row feeds the head) =================
    {
        k_ln<<<dim3(MROWS), dim3(256), 0, stream>>>(x, actA, ln1_g + DMODEL, ln1_b + DMODEL, 1);
        // K,V columns for all rows (N=1024, cols 512..1535 of qkv)
        k_gemm_bf<EPI_NONE, 1><<<dim3(1024/128, MT128, 1), dim3(256), 0, stream>>>(
            actA, qkv_wt + (long)1536 * DMODEL + (long)512 * DMODEL, nullptr, qkv_bf + 512,
            MROWS, DMODEL, 1024, 1536, 0, 0);
        // Q for cls row only
        k_gemv<EPI_NONE, 1><<<dim3(512/64, B_SZ), dim3(256), 0, stream>>>(
            actA, qkv_wt + (long)1536 * DMODEL, nullptr, qkv_bf,
            DMODEL, 512, (long)NTOK * DMODEL, (long)NTOK * 1536);
        // decode attention, split-K over 17 chunks + combine
        k_attn1_sp<<<dim3(NSPLIT1, NHEAD, B_SZ), dim3(256), 0, stream>>>(qkv_bf, mems, pos, dec_part);
        k_attn1_cb<<<dim3(NHEAD, B_SZ), dim3(64), 0, stream>>>(dec_part, actB);
        // out-proj + ff on cls row per batch
        k_gemv<EPI_BIAS_RES, 0><<<dim3(512/64, B_SZ), dim3(256), 0, stream>>>(
            actB, out_wt + (long)DMODEL * DMODEL, out_b + DMODEL, x,
            DMODEL, 512, (long)NTOK * DMODEL, XROW);
        k_ln<<<dim3(B_SZ), dim3(256), 0, stream>>>(x, actA, ln2_g + DMODEL, ln2_b + DMODEL, NTOK);
        k_gemv<EPI_BIAS_GELU, 1><<<dim3(MLPD/64, B_SZ), dim3(256), 0, stream>>>(
            actA, ff1_wt + (long)MLPD * DMODEL, ff_b1 + MLPD, ffbuf,
            DMODEL, MLPD, (long)NTOK * DMODEL, MLPD);
        k_gemv<EPI_BIAS_RES, 0><<<dim3(512/64, B_SZ), dim3(256), 0, stream>>>(
            ffbuf, ff2_wt + (long)DMODEL * MLPD, ff_b2 + DMODEL, x,
            MLPD, 512, MLPD, XROW);
    }

    k_final<<<dim3(B_SZ), dim3(256), 0, stream>>>(x, normf_g, normf_b, fc2_w, fc2_b, out);
}

// Round 10
// 622.697 us; speedup vs baseline: 1.9960x; 1.1989x over previous
//
#include <hip/hip_runtime.h>
#include <hip/hip_bf16.h>
#include <math.h>

// ---------------- problem constants ----------------
#define B_SZ   2
#define NTOK   4097      // n = 4096 + cls
#define KLEN   4105      // n + mem_len(8)
#define KLEN_PAD 4160    // 65 * 64
#define DMODEL 512
#define INDIM  1024
#define NHEAD  8
#define DHEAD  64
#define MLPD   2048
#define MEMLEN 8
#define NEG_BIG  -1.0e30f
#define CSCALE 0.18033688f   // (1/sqrt(64)) * log2(e); softmax runs in log2 domain
#define NQT 65               // q-tiles of 64
#define SPLIT_MID 33         // split0: tiles [0,33), split1: [33,65)
#define NSPLIT1 17           // layer-2 decode: key chunks of 256
#define CH1 256
#define DEFER_THR 8.0f       // defer-max threshold (log2 domain -> factor 256)

typedef unsigned short ushort_t;
typedef short bf16x8 __attribute__((ext_vector_type(8)));
typedef float f32x4  __attribute__((ext_vector_type(4)));

__device__ __forceinline__ unsigned short f2bf(float f) {
    union { float f; unsigned u; } v; v.f = f;
    const unsigned r = v.u + 0x7fff + ((v.u >> 16) & 1);   // RTNE
    return (unsigned short)(r >> 16);
}
__device__ __forceinline__ unsigned short f2bf_rhu(float f) {   // cheap round (positive values)
    union { float f; unsigned u; } v; v.f = f;
    return (unsigned short)((v.u + 0x8000u) >> 16);
}
__device__ __forceinline__ float bf2f(unsigned short u) {
    union { unsigned u; float f; } v; v.u = ((unsigned)u) << 16;
    return v.f;
}

// async global->LDS, 16B per lane; lds base must be wave-uniform
__device__ __forceinline__ void gload_lds16(const void* g, void* l) {
    __builtin_amdgcn_global_load_lds(
        (const __attribute__((address_space(1))) unsigned int*)g,
        (__attribute__((address_space(3))) unsigned int*)l, 16, 0, 0);
}

// ---------------- small helpers ----------------
__device__ __forceinline__ float block_reduce_sum_256(float v, float* sh) {
    #pragma unroll
    for (int m = 1; m < 64; m <<= 1) v += __shfl_xor(v, m);
    const int w = threadIdx.x >> 6;
    if ((threadIdx.x & 63) == 0) sh[w] = v;
    __syncthreads();
    float r = sh[0] + sh[1] + sh[2] + sh[3];
    __syncthreads();
    return r;
}

// ---------------- pos emb (fast trig) ----------------
__global__ void k_pos(float* __restrict__ pos) {
    const int p = blockIdx.x;
    const int j = threadIdx.x;
    const float position = (float)(KLEN - 1 - p);
    const float inv_freq = exp2f(-(float)j * 0.051905126f);   // 10000^(-j/256)
    const float x = position * inv_freq;
    pos[(long)p * DMODEL + j]       = __sinf(x);
    pos[(long)p * DMODEL + 256 + j] = __cosf(x);
}

// ---------------- cls token ----------------
__global__ void k_cls(const float* __restrict__ cls, float* __restrict__ x) {
    const int b = blockIdx.x;
    x[(long)b * NTOK * DMODEL + threadIdx.x] = cls[threadIdx.x];
}

// ---------------- fp32 -> bf16 convert ----------------
__global__ __launch_bounds__(256)
void k_f2b(const float* __restrict__ in, ushort_t* __restrict__ out, long n4) {
    for (long i = blockIdx.x * 256 + threadIdx.x; i < n4; i += (long)gridDim.x * 256) {
        const float4 f = ((const float4*)in)[i];
        ushort4 u;
        u.x = f2bf(f.x); u.y = f2bf(f.y); u.z = f2bf(f.z); u.w = f2bf(f.w);
        ((ushort4*)out)[i] = u;
    }
}

// ---------------- weight fp32[K][N] -> bf16 Wt[N][K] ----------------
__global__ __launch_bounds__(256)
void k_w2bt(const float* __restrict__ W, ushort_t* __restrict__ Wt, int K, int N) {
    __shared__ float tile[64][65];
    W  += (long)blockIdx.z * K * N;
    Wt += (long)blockIdx.z * N * K;
    const int n0 = blockIdx.x * 64, k0 = blockIdx.y * 64;
    const int t = threadIdx.x;
    #pragma unroll
    for (int rep = 0; rep < 16; ++rep) {
        const int idx = rep * 256 + t;
        const int r = idx >> 6, c = idx & 63;
        tile[r][c] = W[(long)(k0 + r) * N + n0 + c];
    }
    __syncthreads();
    #pragma unroll
    for (int rep = 0; rep < 16; ++rep) {
        const int idx = rep * 256 + t;
        const int n = idx >> 6, kk = idx & 63;
        Wt[(long)(n0 + n) * K + k0 + kk] = f2bf(tile[kk][n]);
    }
}

// ---------------- bf16 MFMA GEMM (128x128 tile) ----------------
enum { EPI_NONE = 0, EPI_BIAS_RELU = 1, EPI_BIAS_GELU = 2, EPI_BIAS_RES = 3 };

template <int EPI, int OBF16>
__global__ __launch_bounds__(256)
void k_gemm_bf(const ushort_t* __restrict__ A, const ushort_t* __restrict__ Wt,
               const float* __restrict__ bias, void* __restrict__ Cv,
               int M, int K, int N, long ldc, long sAb, long sCb)
{
    __shared__ ushort_t As[128 * 64];
    __shared__ ushort_t Bs[128 * 64];
    const int t    = threadIdx.x;
    const int lane = t & 63;
    const int w    = t >> 6;
    const int l15  = lane & 15;
    const int lhi  = lane >> 4;
    const int wr   = w >> 1, wc = w & 1;
    const long bm = (long)blockIdx.y * 128, bn = (long)blockIdx.x * 128;
    A += (long)blockIdx.z * sAb;
    float*    Cf = (float*)Cv    + (long)blockIdx.z * sCb;
    ushort_t* Cb = (ushort_t*)Cv + (long)blockIdx.z * sCb;

    int srow[4], scol[4];
    #pragma unroll
    for (int i = 0; i < 4; ++i) {
        const int c = i * 256 + t;
        srow[i] = c >> 3;
        scol[i] = ((c & 7) ^ (srow[i] & 7)) << 3;
    }

    f32x4 acc[4][4] = {};

    for (int k0 = 0; k0 < K; k0 += 64) {
        __syncthreads();
        #pragma unroll
        for (int i = 0; i < 4; ++i) {
            long ar = bm + srow[i]; if (ar >= M) ar = M - 1;
            gload_lds16(A + ar * (long)K + k0 + scol[i],
                        &As[(i * 256 + (t & ~63)) * 8]);
        }
        #pragma unroll
        for (int i = 0; i < 4; ++i) {
            gload_lds16(Wt + (bn + srow[i]) * (long)K + k0 + scol[i],
                        &Bs[(i * 256 + (t & ~63)) * 8]);
        }
        asm volatile("s_waitcnt vmcnt(0)" ::: "memory");
        __syncthreads();

        #pragma unroll
        for (int ks = 0; ks < 2; ++ks) {
            bf16x8 af[4], bfr[4];
            #pragma unroll
            for (int m = 0; m < 4; ++m) {
                const int row = wr * 64 + m * 16 + l15;
                const int cb  = (ks * 64 + lhi * 16) ^ ((row & 7) << 4);
                af[m] = *(const bf16x8*)((const char*)As + row * 128 + cb);
            }
            #pragma unroll
            for (int n = 0; n < 4; ++n) {
                const int row = wc * 64 + n * 16 + l15;
                const int cb  = (ks * 64 + lhi * 16) ^ ((row & 7) << 4);
                bfr[n] = *(const bf16x8*)((const char*)Bs + row * 128 + cb);
            }
            #pragma unroll
            for (int m = 0; m < 4; ++m)
                #pragma unroll
                for (int n = 0; n < 4; ++n)
                    acc[m][n] = __builtin_amdgcn_mfma_f32_16x16x32_bf16(af[m], bfr[n], acc[m][n], 0, 0, 0);
        }
    }

    #pragma unroll
    for (int m = 0; m < 4; ++m) {
        #pragma unroll
        for (int j = 0; j < 4; ++j) {
            const long mg = bm + wr * 64 + m * 16 + lhi * 4 + j;
            if (mg < M) {
                #pragma unroll
                for (int n = 0; n < 4; ++n) {
                    const long ng = bn + wc * 64 + n * 16 + l15;
                    float r = acc[m][n][j];
                    if (EPI != EPI_NONE) r += bias[ng];
                    if (EPI == EPI_BIAS_RELU) r = fmaxf(r, 0.f);
                    if (EPI == EPI_BIAS_GELU) r = 0.5f * r * (1.f + erff(r * 0.70710678118654752f));
                    if (OBF16) Cb[mg * ldc + ng] = f2bf(r);
                    else if (EPI == EPI_BIAS_RES) Cf[mg * ldc + ng] += r;
                    else Cf[mg * ldc + ng] = r;
                }
            }
        }
    }
}

// ---------------- bf16 MFMA GEMM (64x64 tile — for small-N, occupancy-starved cases) ----------------
template <int EPI, int OBF16>
__global__ __launch_bounds__(256)
void k_gemm_bf64(const ushort_t* __restrict__ A, const ushort_t* __restrict__ Wt,
                 const float* __restrict__ bias, void* __restrict__ Cv,
                 int M, int K, int N, long ldc, long sAb, long sCb)
{
    __shared__ ushort_t As[64 * 64];
    __shared__ ushort_t Bs[64 * 64];
    const int t    = threadIdx.x;
    const int lane = t & 63;
    const int w    = t >> 6;      // wave owns rows w*16..w*16+15
    const int l15  = lane & 15;
    const int lhi  = lane >> 4;
    const long bm = (long)blockIdx.y * 64, bn = (long)blockIdx.x * 64;
    A += (long)blockIdx.z * sAb;
    float*    Cf = (float*)Cv    + (long)blockIdx.z * sCb;
    ushort_t* Cb = (ushort_t*)Cv + (long)blockIdx.z * sCb;

    int srow[2], scol[2];
    #pragma unroll
    for (int i = 0; i < 2; ++i) {
        const int c = i * 256 + t;
        srow[i] = c >> 3;
        scol[i] = ((c & 7) ^ (srow[i] & 7)) << 3;
    }

    f32x4 acc[4] = {};

    for (int k0 = 0; k0 < K; k0 += 64) {
        __syncthreads();
        #pragma unroll
        for (int i = 0; i < 2; ++i) {
            long ar = bm + srow[i]; if (ar >= M) ar = M - 1;
            gload_lds16(A + ar * (long)K + k0 + scol[i],
                        &As[(i * 256 + (t & ~63)) * 8]);
        }
        #pragma unroll
        for (int i = 0; i < 2; ++i) {
            gload_lds16(Wt + (bn + srow[i]) * (long)K + k0 + scol[i],
                        &Bs[(i * 256 + (t & ~63)) * 8]);
        }
        asm volatile("s_waitcnt vmcnt(0)" ::: "memory");
        __syncthreads();

        #pragma unroll
        for (int ks = 0; ks < 2; ++ks) {
            const int rowa = w * 16 + l15;
            const int cba  = (ks * 64 + lhi * 16) ^ ((rowa & 7) << 4);
            const bf16x8 af = *(const bf16x8*)((const char*)As + rowa * 128 + cba);
            #pragma unroll
            for (int n = 0; n < 4; ++n) {
                const int rowb = n * 16 + l15;
                const int cbb  = (ks * 64 + lhi * 16) ^ ((rowb & 7) << 4);
                const bf16x8 bfr = *(const bf16x8*)((const char*)Bs + rowb * 128 + cbb);
                acc[n] = __builtin_amdgcn_mfma_f32_16x16x32_bf16(af, bfr, acc[n], 0, 0, 0);
            }
        }
    }

    #pragma unroll
    for (int j = 0; j < 4; ++j) {
        const long mg = bm + w * 16 + lhi * 4 + j;
        if (mg < M) {
            #pragma unroll
            for (int n = 0; n < 4; ++n) {
                const long ng = bn + n * 16 + l15;
                float r = acc[n][j];
                if (EPI != EPI_NONE) r += bias[ng];
                if (EPI == EPI_BIAS_RELU) r = fmaxf(r, 0.f);
                if (EPI == EPI_BIAS_GELU) r = 0.5f * r * (1.f + erff(r * 0.70710678118654752f));
                if (OBF16) Cb[mg * ldc + ng] = f2bf(r);
                else if (EPI == EPI_BIAS_RES) Cf[mg * ldc + ng] += r;
                else Cf[mg * ldc + ng] = r;
            }
        }
    }
}

// ---------------- GEMV (M=1 per batch) ----------------
template <int EPI, int OBF16>
__global__ __launch_bounds__(256)
void k_gemv(const ushort_t* __restrict__ A, const ushort_t* __restrict__ Wt,
            const float* __restrict__ bias, void* __restrict__ Cv,
            int K, int N, long sA, long sC)
{
    const int b = blockIdx.y;
    const int n = blockIdx.x * 64 + (threadIdx.x >> 2);
    const int j = threadIdx.x & 3;
    const ushort_t* a = A + (long)b * sA;
    const ushort_t* wv = Wt + (long)n * K;
    float sum = 0.f;
    for (int k0 = j * 8; k0 < K; k0 += 32) {
        const bf16x8 av = *(const bf16x8*)(a + k0);
        const bf16x8 wr = *(const bf16x8*)(wv + k0);
        #pragma unroll
        for (int e = 0; e < 8; ++e)
            sum += bf2f((ushort_t)av[e]) * bf2f((ushort_t)wr[e]);
    }
    sum += __shfl_xor(sum, 1);
    sum += __shfl_xor(sum, 2);
    if (j == 0 && n < N) {
        float r = sum;
        if (EPI != EPI_NONE) r += bias[n];
        if (EPI == EPI_BIAS_GELU) r = 0.5f * r * (1.f + erff(r * 0.70710678118654752f));
        if (OBF16) ((ushort_t*)Cv)[(long)b * sC + n] = f2bf(r);
        else if (EPI == EPI_BIAS_RES) ((float*)Cv)[(long)b * sC + n] += r;
        else ((float*)Cv)[(long)b * sC + n] = r;
    }
}

// ---------------- LayerNorm, bf16 out ----------------
__global__ __launch_bounds__(256)
void k_ln(const float* __restrict__ x, ushort_t* __restrict__ y,
          const float* __restrict__ g, const float* __restrict__ b, long rstride)
{
    __shared__ float sh[4];
    const long row = (long)blockIdx.x * rstride;
    const float* xr = x + row * DMODEL;
    const int t = threadIdx.x;
    const float v0 = xr[t], v1 = xr[t + 256];
    const float s  = block_reduce_sum_256(v0 + v1, sh);
    const float s2 = block_reduce_sum_256(v0 * v0 + v1 * v1, sh);
    const float mu = s * (1.f / DMODEL);
    const float var = s2 * (1.f / DMODEL) - mu * mu;
    const float rs = rsqrtf(var + 1e-5f);
    y[row * DMODEL + t]       = f2bf((v0 - mu) * rs * g[t] + b[t]);
    y[row * DMODEL + t + 256] = f2bf((v1 - mu) * rs * g[t + 256] + b[t + 256]);
}

// ---------------- build bf16 K rows (pre-scaled by CSCALE): [b][klen][512] ----------------
__global__ __launch_bounds__(256)
void k_build_k(const ushort_t* __restrict__ qkvb, const float* __restrict__ mems,
               const float* __restrict__ pos, ushort_t* __restrict__ kf, int layer)
{
    const int b = blockIdx.y;
    const long idx = (long)blockIdx.x * 256 + threadIdx.x;   // over KLEN*128
    const int j  = (int)(idx >> 7);
    const int d0 = (int)(idx & 127) * 4;
    if (j >= KLEN) return;
    float v0, v1, v2, v3;
    if (j < NTOK) {
        const ushort_t* s = qkvb + ((long)b * NTOK + j) * 1536 + 512 + d0;
        v0 = bf2f(s[0]); v1 = bf2f(s[1]); v2 = bf2f(s[2]); v3 = bf2f(s[3]);
    } else {
        const float* mb = mems + (((long)layer * B_SZ + b) * MEMLEN + (j - NTOK)) * DMODEL + d0;
        v0 = mb[0]; v1 = mb[1]; v2 = mb[2]; v3 = mb[3];
    }
    const float4 pe = *(const float4*)(pos + (long)j * DMODEL + d0);
    ushort4 o;
    o.x = f2bf((v0 + pe.x) * CSCALE);
    o.y = f2bf((v1 + pe.y) * CSCALE);
    o.z = f2bf((v2 + pe.z) * CSCALE);
    o.w = f2bf((v3 + pe.w) * CSCALE);
    *(ushort4*)(kf + ((long)b * KLEN + j) * DMODEL + d0) = o;
}

// ---------------- build bf16 V transposed: [b*8+h][d=64][KLEN_PAD] ----------------
__global__ __launch_bounds__(256)
void k_build_vt(const ushort_t* __restrict__ qkvb, const float* __restrict__ mems,
                const float* __restrict__ pos, ushort_t* __restrict__ vt, int layer)
{
    __shared__ ushort_t tile[64][65];
    const int jb = blockIdx.x * 64;
    const int b  = blockIdx.y;
    const int h  = blockIdx.z;
    const int t  = threadIdx.x;
    #pragma unroll
    for (int rep = 0; rep < 16; ++rep) {
        const int idx = rep * 256 + t;
        const int r = idx >> 6, c = idx & 63;
        const int j = jb + r;
        float val = 0.f;
        if (j < NTOK)
            val = bf2f(qkvb[((long)b * NTOK + j) * 1536 + 1024 + h * 64 + c]) + pos[(long)j * DMODEL + h * 64 + c];
        else if (j < KLEN)
            val = mems[(((long)layer * B_SZ + b) * MEMLEN + (j - NTOK)) * DMODEL + h * 64 + c]
                + pos[(long)j * DMODEL + h * 64 + c];
        tile[c][r] = f2bf(val);
    }
    __syncthreads();
    #pragma unroll
    for (int rep = 0; rep < 16; ++rep) {
        const int idx = rep * 256 + t;
        const int d = idx >> 6, r = idx & 63;
        vt[(((long)b * NHEAD + h) * 64 + d) * (long)KLEN_PAD + jb + r] = tile[d][r];
    }
}

// ---------------- MFMA flash attention, KV-split=2, swapped-QK softmax ----------------
// grid: (NQT, 16, B_SZ); blockIdx.y = split*8 + h.
// Swapped QK^T: S^T = mfma(K_frag, Q_frag) -> lane (l15,lhi) holds S[k=n*16+lhi*4+i][q=l15].
// Softmax per lane = 16-reg reduce + 2 shfl. Defer-max skips o-rescale most tiles.
#define LDSP 72

__global__ __launch_bounds__(256)
void k_attn_sp(const ushort_t* __restrict__ qkvb,
               const ushort_t* __restrict__ kf,
               const ushort_t* __restrict__ vt,
               ushort_t* __restrict__ part0,
               ushort_t* __restrict__ part1,
               float2* __restrict__ ml)
{
    __shared__ ushort_t QPs[64][LDSP];  // Q at start, then reused as P (wave-private 16-row strips)
    __shared__ ushort_t Ks [64][LDSP];
    __shared__ ushort_t Vts[64][LDSP];

    const int t     = threadIdx.x;
    const int lane  = t & 63;
    const int w     = t >> 6;
    const int l15   = lane & 15;
    const int lhi   = lane >> 4;
    const int qt    = blockIdx.x;
    const int qb    = qt * 64;
    const int split = blockIdx.y >> 3;
    const int h     = blockIdx.y & 7;
    const int b     = blockIdx.z;
    const int ktBeg = split ? SPLIT_MID : 0;
    const int ktEnd = split ? NQT : SPLIT_MID;
    ushort_t* part  = split ? part1 : part0;

    // ---- stage Q ----
    {
        const int r  = t >> 2;
        const int c0 = (t & 3) * 16;
        const int qg = qb + r;
        uint4 u0 = make_uint4(0,0,0,0), u1 = make_uint4(0,0,0,0);
        if (qg < NTOK) {
            const ushort_t* src = qkvb + ((long)b * NTOK + qg) * 1536 + h * 64 + c0;
            u0 = ((const uint4*)src)[0];
            u1 = ((const uint4*)src)[1];
        }
        *(uint4*)&QPs[r][c0]     = u0;
        *(uint4*)&QPs[r][c0 + 8] = u1;
    }
    __syncthreads();
    bf16x8 q_frag[2];
    #pragma unroll
    for (int ks = 0; ks < 2; ++ks)
        q_frag[ks] = *(const bf16x8*)&QPs[w * 16 + l15][ks * 32 + lhi * 8];

    f32x4 o_frag[4] = {};
    float m_run = NEG_BIG;   // per-lane state for q-row = qb + w*16 + l15
    float l_run = 0.f;

    const ushort_t* kbase = kf + (long)b * KLEN * DMODEL + h * 64;
    const ushort_t* vbase = vt + ((long)b * NHEAD + h) * 64 * (long)KLEN_PAD;

    for (int kt = ktBeg; kt < ktEnd; ++kt) {
        const int kb = kt * 64;
        __syncthreads();   // prev tile fully consumed
        {
            const int r = t >> 2;
            const int jg = kb + r;
            #pragma unroll
            for (int cc = 0; cc < 2; ++cc) {
                const int c8 = (t & 3) * 2 + cc;
                uint4 kv = make_uint4(0u, 0u, 0u, 0u);
                if (jg < KLEN) kv = *(const uint4*)(kbase + (long)jg * DMODEL + c8 * 8);
                *(uint4*)&Ks[r][c8 * 8] = kv;
                const uint4 vv = *(const uint4*)(vbase + (long)r * KLEN_PAD + kb + c8 * 8);
                *(uint4*)&Vts[r][c8 * 8] = vv;
            }
        }
        __syncthreads();

        // ---- S^T = K @ Q^T (swapped operands; log2 domain, scale in K) ----
        f32x4 s_frag[4];
        #pragma unroll
        for (int n = 0; n < 4; ++n) {
            f32x4 acc = {0.f, 0.f, 0.f, 0.f};
            #pragma unroll
            for (int ks = 0; ks < 2; ++ks) {
                const bf16x8 kfr = *(const bf16x8*)&Ks[n * 16 + l15][ks * 32 + lhi * 8];
                acc = __builtin_amdgcn_mfma_f32_16x16x32_bf16(kfr, q_frag[ks], acc, 0, 0, 0);
            }
            s_frag[n] = acc;
        }

        // ---- tail mask: k = kb + n*16 + lhi*4 + i ----
        if (kt == NQT - 1) {
            #pragma unroll
            for (int n = 0; n < 4; ++n)
                #pragma unroll
                for (int i = 0; i < 4; ++i)
                    if (kb + n * 16 + lhi * 4 + i >= KLEN) s_frag[n][i] = NEG_BIG;
        }

        // ---- row max (16 regs + 2 shfl across lhi) ----
        float tmax = NEG_BIG;
        #pragma unroll
        for (int n = 0; n < 4; ++n)
            #pragma unroll
            for (int i = 0; i < 4; ++i)
                tmax = fmaxf(tmax, s_frag[n][i]);
        tmax = fmaxf(tmax, __shfl_xor(tmax, 16));
        tmax = fmaxf(tmax, __shfl_xor(tmax, 32));

        // ---- defer-max: rescale only when some row grew past THR ----
        if (__any(tmax > m_run + DEFER_THR)) {
            const float mnew  = fmaxf(m_run, tmax);
            const float alpha = exp2f(m_run - mnew);
            m_run = mnew;
            l_run *= alpha;
            float al[4];
            #pragma unroll
            for (int i = 0; i < 4; ++i) al[i] = __shfl(alpha, lhi * 4 + i);
            #pragma unroll
            for (int n = 0; n < 4; ++n)
                #pragma unroll
                for (int i = 0; i < 4; ++i)
                    o_frag[n][i] *= al[i];
        }

        // ---- P = exp2(s - m_run); store to wave-private strip; accumulate l ----
        float lsum = 0.f;
        #pragma unroll
        for (int n = 0; n < 4; ++n) {
            ushort4 pk;
            float p0 = exp2f(s_frag[n][0] - m_run);
            float p1 = exp2f(s_frag[n][1] - m_run);
            float p2 = exp2f(s_frag[n][2] - m_run);
            float p3 = exp2f(s_frag[n][3] - m_run);
            lsum += (p0 + p1) + (p2 + p3);
            pk.x = f2bf_rhu(p0); pk.y = f2bf_rhu(p1);
            pk.z = f2bf_rhu(p2); pk.w = f2bf_rhu(p3);
            *(ushort4*)&QPs[w * 16 + l15][n * 16 + lhi * 4] = pk;
        }
        lsum += __shfl_xor(lsum, 16);
        lsum += __shfl_xor(lsum, 32);
        l_run += lsum;

        // ---- O += P @ V (wave-private P; same-wave LDS in-order, no barrier) ----
        #pragma unroll
        for (int n = 0; n < 4; ++n) {
            #pragma unroll
            for (int ks = 0; ks < 2; ++ks) {
                const bf16x8 pa = *(const bf16x8*)&QPs[w * 16 + l15][ks * 32 + lhi * 8];
                const bf16x8 vb = *(const bf16x8*)&Vts[n * 16 + l15][ks * 32 + lhi * 8];
                o_frag[n] = __builtin_amdgcn_mfma_f32_16x16x32_bf16(pa, vb, o_frag[n], 0, 0, 0);
            }
        }
    }

    // ---- epilogue: unnormalized bf16 partial + (m,l) per q-row ----
    #pragma unroll
    for (int i = 0; i < 4; ++i) {
        const int rg = qb + w * 16 + lhi * 4 + i;
        if (rg < NTOK) {
            ushort_t* op = part + ((long)b * NTOK + rg) * DMODEL + h * 64 + l15;
            #pragma unroll
            for (int n = 0; n < 4; ++n) op[n * 16] = f2bf(o_frag[n][i]);
        }
    }
    {
        const int rg = qb + w * 16 + l15;
        if (lhi == 0 && rg < NTOK)
            ml[(((long)split * B_SZ + b) * NHEAD + h) * (NQT * 64) + (long)qt * 64 + w * 16 + l15]
                = make_float2(m_run, l_run);
    }
}

// ---------------- combine the two KV-splits (in place into part0) ----------------
__global__ __launch_bounds__(256)
void k_comb(ushort_t* __restrict__ part0, const ushort_t* __restrict__ part1,
            const float2* __restrict__ ml)
{
    const int qt = blockIdx.x, h = blockIdx.y, b = blockIdx.z;
    const int t  = threadIdx.x;
    const int r  = t >> 2;
    const int c0 = (t & 3) * 16;
    const int rg = qt * 64 + r;
    if (rg >= NTOK) return;
    const long mli = ((long)b * NHEAD + h) * (NQT * 64) + (long)qt * 64 + r;
    const float2 a0 = ml[mli];
    const float2 a1 = ml[(long)B_SZ * NHEAD * NQT * 64 + mli];
    const float M  = fmaxf(a0.x, a1.x);
    const float e0 = exp2f(a0.x - M);
    const float e1 = exp2f(a1.x - M);
    const float inv = 1.f / (a0.y * e0 + a1.y * e1);
    ushort_t*       p0 = part0 + ((long)b * NTOK + rg) * DMODEL + h * 64 + c0;
    const ushort_t* p1 = part1 + ((long)b * NTOK + rg) * DMODEL + h * 64 + c0;
    #pragma unroll
    for (int c = 0; c < 16; ++c)
        p0[c] = f2bf((bf2f(p0[c]) * e0 + bf2f(p1[c]) * e1) * inv);
}

// ---------------- layer-2 decode attention, split-K over 17 chunks of 256 keys ----------------
__global__ __launch_bounds__(256)
void k_attn1_sp(const ushort_t* __restrict__ qkvb, const float* __restrict__ mems,
                const float* __restrict__ pos, float* __restrict__ part)
{
    __shared__ float qs[64];
    __shared__ float sarr[CH1];
    __shared__ float red[4];
    __shared__ float osum[4][64];
    const int sp = blockIdx.x, h = blockIdx.y, b = blockIdx.z;
    const int t = threadIdx.x, w = t >> 6;
    const int j0 = sp * CH1;
    const int jend = min(j0 + CH1, KLEN);

    if (t < 64) qs[t] = bf2f(qkvb[(long)b * NTOK * 1536 + h * 64 + t]);
    __syncthreads();

    const int j = j0 + t;
    float s = NEG_BIG;
    if (j < KLEN) {
        float acc = 0.f;
        const float* pp = pos + (long)j * DMODEL + h * 64;
        if (j < NTOK) {
            const ushort_t* kr = qkvb + ((long)b * NTOK + j) * 1536 + 512 + h * 64;
            #pragma unroll
            for (int d = 0; d < 64; ++d) acc += qs[d] * (bf2f(kr[d]) + pp[d]);
        } else {
            const float* mb = mems + (((long)B_SZ + b) * MEMLEN + (j - NTOK)) * DMODEL + h * 64;
            #pragma unroll
            for (int d = 0; d < 64; ++d) acc += qs[d] * (mb[d] + pp[d]);
        }
        s = acc * CSCALE;
    }
    float mx = s;
    #pragma unroll
    for (int m = 1; m < 64; m <<= 1) mx = fmaxf(mx, __shfl_xor(mx, m));
    if ((t & 63) == 0) red[w] = mx;
    __syncthreads();
    const float M = fmaxf(fmaxf(red[0], red[1]), fmaxf(red[2], red[3]));
    __syncthreads();

    const float p = (j < KLEN) ? exp2f(s - M) : 0.f;
    sarr[t] = p;
    float lsum = p;
    #pragma unroll
    for (int m = 1; m < 64; m <<= 1) lsum += __shfl_xor(lsum, m);
    if ((t & 63) == 0) red[w] = lsum;
    __syncthreads();
    const float L = red[0] + red[1] + red[2] + red[3];

    const int d = t & 63, g = t >> 6;
    float o = 0.f;
    for (int j2 = j0 + g; j2 < jend; j2 += 4) {
        float v;
        if (j2 < NTOK) v = bf2f(qkvb[((long)b * NTOK + j2) * 1536 + 1024 + h * 64 + d]);
        else           v = mems[(((long)B_SZ + b) * MEMLEN + (j2 - NTOK)) * DMODEL + h * 64 + d];
        v += pos[(long)j2 * DMODEL + h * 64 + d];
        o += sarr[j2 - j0] * v;
    }
    osum[g][d] = o;
    __syncthreads();
    if (t < 64) {
        float* pb = part + (((long)b * NHEAD + h) * NSPLIT1 + sp) * 66;
        pb[2 + t] = osum[0][t] + osum[1][t] + osum[2][t] + osum[3][t];
        if (t == 0) { pb[0] = M; pb[1] = L; }
    }
}

// ---------------- combine decode chunks ----------------
__global__ __launch_bounds__(64)
void k_attn1_cb(const float* __restrict__ part, ushort_t* __restrict__ outp)
{
    const int h = blockIdx.x, b = blockIdx.y;
    const int t = threadIdx.x;   // 0..63
    const float* pb = part + ((long)b * NHEAD + h) * NSPLIT1 * 66;
    float M = NEG_BIG;
    #pragma unroll
    for (int c = 0; c < NSPLIT1; ++c) M = fmaxf(M, pb[c * 66]);
    float L = 0.f, o = 0.f;
    #pragma unroll
    for (int c = 0; c < NSPLIT1; ++c) {
        const float e = exp2f(pb[c * 66] - M);
        L += e * pb[c * 66 + 1];
        o += e * pb[c * 66 + 2 + t];
    }
    outp[(long)b * NTOK * DMODEL + h * 64 + t] = f2bf(o / L);
}

// ---------------- final LN + 2-class head on cls row ----------------
__global__ __launch_bounds__(256)
void k_final(const float* __restrict__ x, const float* __restrict__ g,
             const float* __restrict__ bb, const float* __restrict__ w2,
             const float* __restrict__ b2, float* __restrict__ out)
{
    __shared__ float sh[4];
    const int b = blockIdx.x;
    const float* xr = x + (long)b * NTOK * DMODEL;
    const int t = threadIdx.x;
    const float v0 = xr[t], v1 = xr[t + 256];
    const float s  = block_reduce_sum_256(v0 + v1, sh);
    const float s2 = block_reduce_sum_256(v0 * v0 + v1 * v1, sh);
    const float mu = s * (1.f / DMODEL);
    const float var = s2 * (1.f / DMODEL) - mu * mu;
    const float rs = rsqrtf(var + 1e-5f);
    const float n0 = (v0 - mu) * rs * g[t] + bb[t];
    const float n1 = (v1 - mu) * rs * g[t + 256] + bb[t + 256];
    const float p0 = block_reduce_sum_256(n0 * w2[t * 2 + 0] + n1 * w2[(t + 256) * 2 + 0], sh);
    const float p1 = block_reduce_sum_256(n0 * w2[t * 2 + 1] + n1 * w2[(t + 256) * 2 + 1], sh);
    if (t == 0) {
        out[b * 2 + 0] = p0 + b2[0];
        out[b * 2 + 1] = p1 + b2[1];
    }
}

// ---------------- host orchestration ----------------
extern "C" void kernel_launch(void* const* d_in, const int* in_sizes, int n_in,
                              void* d_out, int out_size, void* d_ws, size_t ws_size,
                              hipStream_t stream)
{
    const float* data    = (const float*)d_in[0];
    const float* mems    = (const float*)d_in[1];
    const float* fc1_w   = (const float*)d_in[2];
    const float* fc1_b   = (const float*)d_in[3];
    const float* cls     = (const float*)d_in[4];
    const float* ln1_g   = (const float*)d_in[5];
    const float* ln1_b   = (const float*)d_in[6];
    const float* qkv_w   = (const float*)d_in[7];
    const float* out_w   = (const float*)d_in[8];
    const float* out_b   = (const float*)d_in[9];
    const float* ln2_g   = (const float*)d_in[10];
    const float* ln2_b   = (const float*)d_in[11];
    const float* ff_w1   = (const float*)d_in[12];
    const float* ff_b1   = (const float*)d_in[13];
    const float* ff_w2   = (const float*)d_in[14];
    const float* ff_b2   = (const float*)d_in[15];
    const float* normf_g = (const float*)d_in[16];
    const float* normf_b = (const float*)d_in[17];
    const float* fc2_w   = (const float*)d_in[18];
    const float* fc2_b   = (const float*)d_in[19];
    float* out = (float*)d_out;

    const int MROWS = B_SZ * NTOK;                          // 8194
    const int MT128 = (MROWS + 127) / 128;                  // 65
    const int MT64  = (MROWS + 63) / 64;                    // 129
    const long XROW = (long)NTOK * DMODEL;                  // batch stride in x

    // ---- workspace layout ----
    char* p = (char*)d_ws;
    float* x   = (float*)p;            p += (long)B_SZ * NTOK * DMODEL * 4;
    float* pos = (float*)p;            p += (long)KLEN * DMODEL * 4;
    ushort_t* data_bf = (ushort_t*)p;  p += (long)B_SZ * 4096 * INDIM * 2;    // dead post-fc1 -> attn partials
    ushort_t* actA    = (ushort_t*)p;  p += (long)MROWS * DMODEL * 2;
    ushort_t* actB    = (ushort_t*)p;  p += (long)MROWS * DMODEL * 2;
    ushort_t* fc1_wt  = (ushort_t*)p;  p += (long)DMODEL * INDIM * 2;
    ushort_t* qkv_wt  = (ushort_t*)p;  p += (long)2 * 1536 * DMODEL * 2;
    ushort_t* out_wt  = (ushort_t*)p;  p += (long)2 * DMODEL * DMODEL * 2;
    ushort_t* ff1_wt  = (ushort_t*)p;  p += (long)2 * MLPD * DMODEL * 2;
    ushort_t* ff2_wt  = (ushort_t*)p;  p += (long)2 * DMODEL * MLPD * 2;
    ushort_t* qkv_bf  = (ushort_t*)p;                                   // [8194][1536]
    ushort_t* kf      = qkv_bf + (long)MROWS * 1536;                    // [2][4105][512]
    ushort_t* vt      = kf + (long)B_SZ * KLEN * DMODEL;                // [16][64][4160]
    ushort_t* ffbuf   = qkv_bf;                                         // overlays

    // attn partial overlays (data_bf is dead after fc1)
    ushort_t* part1 = data_bf;                                          // [B][NTOK][512] bf16
    float2*   mlbuf = (float2*)(data_bf + (long)B_SZ * NTOK * DMODEL);  // [2][B][8][65*64]
    float*    dec_part = (float*)(mlbuf + (long)2 * B_SZ * NHEAD * NQT * 64); // [B][8][17][66]

    // ---- one-time converts ----
    k_f2b<<<dim3(2048), dim3(256), 0, stream>>>(data, data_bf, (long)B_SZ * 4096 * INDIM / 4);
    k_w2bt<<<dim3(DMODEL/64, INDIM/64, 1),  dim3(256), 0, stream>>>(fc1_w, fc1_wt, INDIM, DMODEL);
    k_w2bt<<<dim3(1536/64, DMODEL/64, 2),   dim3(256), 0, stream>>>(qkv_w, qkv_wt, DMODEL, 1536);
    k_w2bt<<<dim3(DMODEL/64, DMODEL/64, 2), dim3(256), 0, stream>>>(out_w, out_wt, DMODEL, DMODEL);
    k_w2bt<<<dim3(MLPD/64, DMODEL/64, 2),   dim3(256), 0, stream>>>(ff_w1, ff1_wt, DMODEL, MLPD);
    k_w2bt<<<dim3(DMODEL/64, MLPD/64, 2),   dim3(256), 0, stream>>>(ff_w2, ff2_wt, MLPD, DMODEL);

    k_pos<<<dim3(KLEN), dim3(256), 0, stream>>>(pos);
    k_cls<<<dim3(B_SZ), dim3(512), 0, stream>>>(cls, x);

    // fc1 + ReLU -> x rows 1..4096 per batch (fp32 out); 64^2 tile for occupancy
    k_gemm_bf64<EPI_BIAS_RELU, 0><<<dim3(DMODEL/64, 4096/64, B_SZ), dim3(256), 0, stream>>>(
        data_bf, fc1_wt, fc1_b, x + DMODEL, 4096, INDIM, DMODEL, DMODEL,
        (long)4096 * INDIM, XROW);

    const int KBK = (KLEN * 128 + 255) / 256;

    // ================= layer 0 (full) =================
    {
        k_ln<<<dim3(MROWS), dim3(256), 0, stream>>>(x, actA, ln1_g, ln1_b, 1);
        k_gemm_bf<EPI_NONE, 1><<<dim3(1536/128, MT128, 1), dim3(256), 0, stream>>>(
            actA, qkv_wt, nullptr, qkv_bf, MROWS, DMODEL, 1536, 1536, 0, 0);
        k_build_k <<<dim3(KBK, B_SZ), dim3(256), 0, stream>>>(qkv_bf, mems, pos, kf, 0);
        k_build_vt<<<dim3(KLEN_PAD/64, B_SZ, NHEAD), dim3(256), 0, stream>>>(qkv_bf, mems, pos, vt, 0);
        k_attn_sp<<<dim3(NQT, 16, B_SZ), dim3(256), 0, stream>>>(qkv_bf, kf, vt, actB, part1, mlbuf);
        k_comb   <<<dim3(NQT, NHEAD, B_SZ), dim3(256), 0, stream>>>(actB, part1, mlbuf);
        k_gemm_bf64<EPI_BIAS_RES, 0><<<dim3(DMODEL/64, MT64, 1), dim3(256), 0, stream>>>(
            actB, out_wt, out_b, x, MROWS, DMODEL, DMODEL, DMODEL, 0, 0);
        k_ln<<<dim3(MROWS), dim3(256), 0, stream>>>(x, actA, ln2_g, ln2_b, 1);
        k_gemm_bf<EPI_BIAS_GELU, 1><<<dim3(MLPD/128, MT128, 1), dim3(256), 0, stream>>>(
            actA, ff1_wt, ff_b1, ffbuf, MROWS, DMODEL, MLPD, MLPD, 0, 0);
        k_gemm_bf64<EPI_BIAS_RES, 0><<<dim3(DMODEL/64, MT64, 1), dim3(256), 0, stream>>>(
            ffbuf, ff2_wt, ff_b2, x, MROWS, MLPD, DMODEL, DMODEL, 0, 0);
    }

    // ================= layer 1 (only cls row feeds the head) =================
    {
        k_ln<<<dim3(MROWS), dim3(256), 0, stream>>>(x, actA, ln1_g + DMODEL, ln1_b + DMODEL, 1);
        // K,V columns for all rows (N=1024, cols 512..1535 of qkv)
        k_gemm_bf<EPI_NONE, 1><<<dim3(1024/128, MT128, 1), dim3(256), 0, stream>>>(
            actA, qkv_wt + (long)1536 * DMODEL + (long)512 * DMODEL, nullptr, qkv_bf + 512,
            MROWS, DMODEL, 1024, 1536, 0, 0);
        // Q for cls row only
        k_gemv<EPI_NONE, 1><<<dim3(512/64, B_SZ), dim3(256), 0, stream>>>(
            actA, qkv_wt + (long)1536 * DMODEL, nullptr, qkv_bf,
            DMODEL, 512, (long)NTOK * DMODEL, (long)NTOK * 1536);
        // decode attention, split-K over 17 chunks + combine
        k_attn1_sp<<<dim3(NSPLIT1, NHEAD, B_SZ), dim3(256), 0, stream>>>(qkv_bf, mems, pos, dec_part);
        k_attn1_cb<<<dim3(NHEAD, B_SZ), dim3(64), 0, stream>>>(dec_part, actB);
        // out-proj + ff on cls row per batch
        k_gemv<EPI_BIAS_RES, 0><<<dim3(512/64, B_SZ), dim3(256), 0, stream>>>(
            actB, out_wt + (long)DMODEL * DMODEL, out_b + DMODEL, x,
            DMODEL, 512, (long)NTOK * DMODEL, XROW);
        k_ln<<<dim3(B_SZ), dim3(256), 0, stream>>>(x, actA, ln2_g + DMODEL, ln2_b + DMODEL, NTOK);
        k_gemv<EPI_BIAS_GELU, 1><<<dim3(MLPD/64, B_SZ), dim3(256), 0, stream>>>(
            actA, ff1_wt + (long)MLPD * DMODEL, ff_b1 + MLPD, ffbuf,
            DMODEL, MLPD, (long)NTOK * DMODEL, MLPD);
        k_gemv<EPI_BIAS_RES, 0><<<dim3(512/64, B_SZ), dim3(256), 0, stream>>>(
            ffbuf, ff2_wt + (long)DMODEL * MLPD, ff_b2 + DMODEL, x,
            MLPD, 512, MLPD, XROW);
    }

    k_final<<<dim3(B_SZ), dim3(256), 0, stream>>>(x, normf_g, normf_b, fc2_w, fc2_b, out);
}